// Round 7
// baseline (344.312 us; speedup 1.0000x reference)
//
#include <hip/hip_runtime.h>
#include <math.h>

#define SCALE 0.17677669529663687f  /* (256/8)^-0.5 */

typedef short short8 __attribute__((ext_vector_type(8)));
typedef float f32x4 __attribute__((ext_vector_type(4)));

// ---------------------------------------------------------------------------
__device__ __forceinline__ int token_row_addr(int m) {
    int b = m / 3136;
    int rem = m - b * 3136;
    int s = rem / 49;
    int tok = rem - s * 49;
    int h = (s >> 3) * 7 + tok / 7;
    int w = (s & 7) * 7 + (tok % 7);
    return (b * 56 + h) * 56 + w;
}

__device__ __forceinline__ void split2(float x, unsigned short& h, unsigned short& l) {
    unsigned int u = __float_as_uint(x);
    h = (unsigned short)(u >> 16);
    float hf = __uint_as_float(u & 0xFFFF0000u);
    l = (unsigned short)(__float_as_uint(x - hf) >> 16);
}

__device__ __forceinline__ unsigned int pack2(float x) {
    unsigned short h, l;
    split2(x, h, l);
    return ((unsigned int)h << 16) | l;
}

__device__ __forceinline__ float b2f(unsigned short u) {
    return __uint_as_float(((unsigned int)u) << 16);
}

__device__ __forceinline__ float unpack_f(unsigned int u) {
    return b2f((unsigned short)(u >> 16)) + b2f((unsigned short)(u & 0xFFFFu));
}

__device__ __forceinline__ void unpack_u4(uint4 a, uint4 b, short8& h, short8& l) {
    h[0] = (short)(a.x >> 16); l[0] = (short)(a.x & 0xFFFFu);
    h[1] = (short)(a.y >> 16); l[1] = (short)(a.y & 0xFFFFu);
    h[2] = (short)(a.z >> 16); l[2] = (short)(a.z & 0xFFFFu);
    h[3] = (short)(a.w >> 16); l[3] = (short)(a.w & 0xFFFFu);
    h[4] = (short)(b.x >> 16); l[4] = (short)(b.x & 0xFFFFu);
    h[5] = (short)(b.y >> 16); l[5] = (short)(b.y & 0xFFFFu);
    h[6] = (short)(b.z >> 16); l[6] = (short)(b.z & 0xFFFFu);
    h[7] = (short)(b.w >> 16); l[7] = (short)(b.w & 0xFFFFu);
}

__device__ __forceinline__ void load_unpack8(const unsigned int* g, short8& h, short8& l) {
    uint4 a = *(const uint4*)g;
    uint4 b = *(const uint4*)(g + 4);
    unpack_u4(a, b, h, l);
}

__device__ __forceinline__ void gload16(const unsigned short* g, unsigned short* l) {
    __builtin_amdgcn_global_load_lds(
        (const __attribute__((address_space(1))) unsigned int*)g,
        (__attribute__((address_space(3))) unsigned int*)l, 16, 0, 0);
}

// ---------------------------------------------------------------------------
// converters
__global__ void k_cvt_x(const float* __restrict__ x, unsigned short* __restrict__ xhi,
                        unsigned short* __restrict__ xlo) {
    int m = blockIdx.x;
    int k = threadIdx.x;
    float v = x[(size_t)token_row_addr(m) * 256 + k];
    unsigned short h, l;
    split2(v, h, l);
    xhi[(size_t)m * 256 + k] = h;
    xlo[(size_t)m * 256 + k] = l;
}

__global__ void k_cvt_w(const float* __restrict__ w, int ncols,
                        unsigned short* __restrict__ whi, unsigned short* __restrict__ wlo) {
    int n = blockIdx.x;
    int k = threadIdx.x;
    float v = w[(size_t)k * ncols + n];
    unsigned short h, l;
    split2(v, h, l);
    whi[(size_t)n * 256 + k] = h;
    wlo[(size_t)n * 256 + k] = l;
}

// ---------------------------------------------------------------------------
// K0: fused region path: mean -> qkv_r -> gating. grid 512, block 256.
__global__ void k_region_fused(const float* __restrict__ x, const float* __restrict__ wqkv,
                               const float* __restrict__ bqkv, const float* __restrict__ wg1,
                               const float* __restrict__ bg1, const float* __restrict__ wg2,
                               const float* __restrict__ bg2, float* __restrict__ qkvr,
                               float* __restrict__ sig) {
    __shared__ float xs[256];
    __shared__ float qbuf[256];
    __shared__ float hs[64];
    int blk = blockIdx.x;
    int b = blk >> 6, s = blk & 63;
    int t = threadIdx.x;
    int hy0 = (s >> 3) * 7, wx0 = (s & 7) * 7;
    const float* xb = x + ((size_t)b * 56 * 56) * 256 + t;
    float sum = 0.f;
#pragma unroll 1
    for (int tt = 0; tt < 49; ++tt) {
        int h = hy0 + tt / 7, w = wx0 + (tt % 7);
        sum += xb[(size_t)(h * 56 + w) * 256];
    }
    xs[t] = sum * (1.0f / 49.0f);
    __syncthreads();

    float a0 = 0.f, a1 = 0.f, a2 = 0.f;
#pragma unroll 4
    for (int k = 0; k < 256; ++k) {
        float xv = xs[k];
        const float* wrow = wqkv + (size_t)k * 768;
        a0 += xv * wrow[t];
        a1 += xv * wrow[t + 256];
        a2 += xv * wrow[t + 512];
    }
    float q = a0 + bqkv[t];
    qbuf[t] = q;
    float* o = qkvr + (size_t)blk * 768;
    o[t]       = q;
    o[t + 256] = a1 + bqkv[t + 256];
    o[t + 512] = a2 + bqkv[t + 512];
    __syncthreads();

    if (t < 64) {
        float acc = bg1[t];
#pragma unroll 4
        for (int k = 0; k < 256; ++k) acc += qbuf[k] * wg1[(size_t)k * 64 + t];
        hs[t] = fmaxf(acc, 0.f);
    }
    __syncthreads();
    if (t < 2) {
        float gp = bg2[t];
#pragma unroll 1
        for (int m = 0; m < 64; ++m) gp += hs[m] * wg2[m * 2 + t];
        float sp = fmaxf(gp, 0.f) + log1pf(expf(-fabsf(gp)));
        sig[blk * 2 + t] = sp + 0.5f;
    }
}

__global__ void k_topk_gauss(const float* __restrict__ qkvr, const float* __restrict__ sig,
                             int* __restrict__ topk, float* __restrict__ gwt) {
    __shared__ float A[64];
    __shared__ float G[64];
    __shared__ int idxs[4];
    __shared__ float gsum_s;
    int blk = blockIdx.x;
    int b = blk >> 6, s = blk & 63;
    int z = threadIdx.x;
    const float* qr = qkvr + (size_t)blk * 768;
    const float* kr = qkvr + (size_t)(b * 64 + z) * 768 + 256;
    float acc = 0.f;
#pragma unroll 4
    for (int k = 0; k < 256; k += 4) {
        float4 q4 = *(const float4*)(qr + k);
        float4 k4 = *(const float4*)(kr + k);
        acc += q4.x * k4.x + q4.y * k4.y + q4.z * k4.z + q4.w * k4.w;
    }
    A[z] = acc * SCALE;
    float s0 = sig[blk * 2 + 0], s1 = sig[blk * 2 + 1];
    float dx = (float)((z & 7) - (s & 7));
    float dy = (float)((z >> 3) - (s >> 3));
    float t0 = dx / s0, t1 = dy / s1;
    float zz = t0 * t0 + t1 * t1;
    G[z] = expf(-0.5f * zz);
    __syncthreads();
    if (z == 0) {
        float gs = 0.f;
        for (int m = 0; m < 64; ++m) gs += G[m];
        gsum_s = gs + 1e-6f;
        for (int it = 0; it < 4; ++it) {
            int best = 0;
            float bv = A[0];
            for (int m = 1; m < 64; ++m) {
                if (A[m] > bv) { bv = A[m]; best = m; }
            }
            idxs[it] = best;
            A[best] = -3.0e38f;
        }
    }
    __syncthreads();
    if (z < 4) {
        int id = idxs[z];
        topk[blk * 4 + z] = id;
        gwt[blk * 4 + z] = G[id] / gsum_s;
    }
}

// ---------------------------------------------------------------------------
// K1: qkv GEMM, split-bf16 MFMA, 128x128 tile, BK=32. grid (6, 196).
__global__ __launch_bounds__(256) void k_mm_qkv(
    const unsigned short* __restrict__ xhi, const unsigned short* __restrict__ xlo,
    const unsigned short* __restrict__ whi, const unsigned short* __restrict__ wlo,
    const float* __restrict__ bqkv,
    unsigned int* __restrict__ Qp, unsigned int* __restrict__ Kp,
    unsigned int* __restrict__ Vp) {
    __shared__ __align__(16) unsigned short Ah[4096];
    __shared__ __align__(16) unsigned short Al[4096];
    __shared__ __align__(16) unsigned short Bh[4096];
    __shared__ __align__(16) unsigned short Bl[4096];
    int tid = threadIdx.x;
    int ln = tid & 63, wv = tid >> 6;
    int m0 = blockIdx.y * 128, n0 = blockIdx.x * 128;
    int mrow = (wv >> 1) * 64, ncol = (wv & 1) * 64;

    int lrow = ln >> 2, lseg = (ln & 3) * 8;
    const unsigned short* gA0 = xhi + (size_t)(m0 + wv * 32 + lrow) * 256 + lseg;
    const unsigned short* gA1 = gA0 + 16 * 256;
    const unsigned short* gAl0 = xlo + (size_t)(m0 + wv * 32 + lrow) * 256 + lseg;
    const unsigned short* gAl1 = gAl0 + 16 * 256;
    const unsigned short* gB0 = whi + (size_t)(n0 + wv * 32 + lrow) * 256 + lseg;
    const unsigned short* gB1 = gB0 + 16 * 256;
    const unsigned short* gBl0 = wlo + (size_t)(n0 + wv * 32 + lrow) * 256 + lseg;
    const unsigned short* gBl1 = gBl0 + 16 * 256;
    unsigned short* lA0 = &Ah[(wv * 32) * 32];
    unsigned short* lA1 = &Ah[(wv * 32 + 16) * 32];
    unsigned short* lAl0 = &Al[(wv * 32) * 32];
    unsigned short* lAl1 = &Al[(wv * 32 + 16) * 32];
    unsigned short* lB0 = &Bh[(wv * 32) * 32];
    unsigned short* lB1 = &Bh[(wv * 32 + 16) * 32];
    unsigned short* lBl0 = &Bl[(wv * 32) * 32];
    unsigned short* lBl1 = &Bl[(wv * 32 + 16) * 32];

    int fm = ln & 15, fq = (ln >> 4) * 8;
    f32x4 acc[4][4];
#pragma unroll
    for (int i = 0; i < 4; ++i)
#pragma unroll
        for (int j = 0; j < 4; ++j) acc[i][j] = (f32x4){0.f, 0.f, 0.f, 0.f};

#pragma unroll 1
    for (int kc = 0; kc < 8; ++kc) {
        if (kc) __syncthreads();
        gload16(gA0, lA0); gload16(gA1, lA1);
        gload16(gAl0, lAl0); gload16(gAl1, lAl1);
        gload16(gB0, lB0); gload16(gB1, lB1);
        gload16(gBl0, lBl0); gload16(gBl1, lBl1);
        gA0 += 32; gA1 += 32; gAl0 += 32; gAl1 += 32;
        gB0 += 32; gB1 += 32; gBl0 += 32; gBl1 += 32;
        __syncthreads();

        short8 ah[4], bh[4], xx[4];
#pragma unroll
        for (int mi = 0; mi < 4; ++mi)
            ah[mi] = *(const short8*)&Ah[(mrow + mi * 16 + fm) * 32 + fq];
#pragma unroll
        for (int ni = 0; ni < 4; ++ni)
            bh[ni] = *(const short8*)&Bh[(ncol + ni * 16 + fm) * 32 + fq];
#pragma unroll
        for (int mi = 0; mi < 4; ++mi)
#pragma unroll
            for (int ni = 0; ni < 4; ++ni)
                acc[mi][ni] = __builtin_amdgcn_mfma_f32_16x16x32_bf16(ah[mi], bh[ni], acc[mi][ni], 0, 0, 0);
#pragma unroll
        for (int mi = 0; mi < 4; ++mi)
            xx[mi] = *(const short8*)&Al[(mrow + mi * 16 + fm) * 32 + fq];
#pragma unroll
        for (int mi = 0; mi < 4; ++mi)
#pragma unroll
            for (int ni = 0; ni < 4; ++ni)
                acc[mi][ni] = __builtin_amdgcn_mfma_f32_16x16x32_bf16(xx[mi], bh[ni], acc[mi][ni], 0, 0, 0);
#pragma unroll
        for (int ni = 0; ni < 4; ++ni)
            xx[ni] = *(const short8*)&Bl[(ncol + ni * 16 + fm) * 32 + fq];
#pragma unroll
        for (int mi = 0; mi < 4; ++mi)
#pragma unroll
            for (int ni = 0; ni < 4; ++ni)
                acc[mi][ni] = __builtin_amdgcn_mfma_f32_16x16x32_bf16(ah[mi], xx[ni], acc[mi][ni], 0, 0, 0);
    }

    int nb = n0 >> 7;
    unsigned int* dst = (nb < 2) ? Qp : (nb < 4) ? Kp : Vp;
    int qrow = (ln >> 4) * 4;
#pragma unroll
    for (int ni = 0; ni < 4; ++ni) {
        int col = (n0 & 255) + ncol + ni * 16 + fm;
        float bias = bqkv[n0 + ncol + ni * 16 + fm];
#pragma unroll
        for (int mi = 0; mi < 4; ++mi) {
#pragma unroll
            for (int r = 0; r < 4; ++r) {
                int m = m0 + mrow + mi * 16 + qrow + r;
                dst[(size_t)m * 256 + col] = pack2(acc[mi][ni][r] + bias);
            }
        }
    }
}

// ---------------------------------------------------------------------------
// K1b: transpose Vp -> Vtp[win][c][64] packed (pads zeroed) AND fused dwconv
// -> ATTp initial value. grid 512, block 256.
__global__ __launch_bounds__(256) void k_transpose_v(
    const unsigned int* __restrict__ Vp, unsigned int* __restrict__ Vtp,
    const float* __restrict__ dwk, const float* __restrict__ dwb,
    unsigned int* __restrict__ ATTp) {
    __shared__ unsigned int T[49][257];
    int win = blockIdx.x;
    int tid = threadIdx.x;
#pragma unroll 1
    for (int i = tid; i < 49 * 64; i += 256) {
        int tok = i >> 6, cq = (i & 63) * 4;
        uint4 v = *(const uint4*)&Vp[((size_t)win * 49 + tok) * 256 + cq];
        T[tok][cq + 0] = v.x;
        T[tok][cq + 1] = v.y;
        T[tok][cq + 2] = v.z;
        T[tok][cq + 3] = v.w;
    }
    __syncthreads();
#pragma unroll 1
    for (int it = 0; it < 8; ++it) {
        int item = tid + it * 256;
        int c = item >> 3, t8 = (item & 7) * 8;
        uint4 o0, o1;
        o0.x = (t8 + 0 < 49) ? T[t8 + 0][c] : 0u;
        o0.y = (t8 + 1 < 49) ? T[t8 + 1][c] : 0u;
        o0.z = (t8 + 2 < 49) ? T[t8 + 2][c] : 0u;
        o0.w = (t8 + 3 < 49) ? T[t8 + 3][c] : 0u;
        o1.x = (t8 + 4 < 49) ? T[t8 + 4][c] : 0u;
        o1.y = (t8 + 5 < 49) ? T[t8 + 5][c] : 0u;
        o1.z = (t8 + 6 < 49) ? T[t8 + 6][c] : 0u;
        o1.w = (t8 + 7 < 49) ? T[t8 + 7][c] : 0u;
        size_t o = (size_t)win * 16384 + (size_t)c * 64 + t8;
        *(uint4*)&Vtp[o] = o0;
        *(uint4*)&Vtp[o + 4] = o1;
    }

    // fused dwconv: thread tid owns channel c = tid for all 49 tokens.
    {
        int c = tid;
        float dk[9];
#pragma unroll
        for (int t = 0; t < 9; ++t) dk[t] = dwk[(size_t)t * 256 + c];
        float db = dwb[c];
#pragma unroll 1
        for (int py = 0; py < 7; ++py) {
#pragma unroll 1
            for (int px = 0; px < 7; ++px) {
                float vd = db;
#pragma unroll
                for (int dy = 0; dy < 3; ++dy) {
                    int yy = py + dy - 1;
                    if (yy < 0 || yy > 6) continue;   // wave-uniform branch
#pragma unroll
                    for (int dx = 0; dx < 3; ++dx) {
                        int xx = px + dx - 1;
                        if (xx < 0 || xx > 6) continue;  // wave-uniform branch
                        vd += unpack_f(T[yy * 7 + xx][c]) * dk[dy * 3 + dx];
                    }
                }
                int w = py * 7 + px;
                ATTp[((size_t)win * 49 + w) * 256 + c] = pack2(vd);
            }
        }
    }
}

// ---------------------------------------------------------------------------
// K2: FUSED attention, MERGED halves: one 512-thread block per window.
// grid 512. blk: batch=blk&7 (XCD), win=(batch<<6)|(blk>>3).
// Phase 1: wave wv -> (half wh=wv>>2, region rwv=wv&3). Both halves' same-
// region waves issue identical K addresses -> L1/L2 reuse (was 2x HBM fetch).
// Phase 2: wave -> (half, 64-col strip); same-strip waves share Vtp lines.
// Ps[64][260] (~69 KB LDS total, 2 blocks/CU, 16 waves/CU).
__global__ __launch_bounds__(512) void k_attn(
    const unsigned int* __restrict__ Qp, const unsigned int* __restrict__ Kp,
    const unsigned int* __restrict__ Vtp,
    const int* __restrict__ topk, const float* __restrict__ gwt,
    unsigned int* __restrict__ ATTp) {
    __shared__ __align__(16) unsigned int Ps[64][260];
    __shared__ float redm[8][32];
    __shared__ float reds[8][32];
    __shared__ float gmax[64];
    __shared__ float ginv[64];
    __shared__ int regs_s[4];
    int blk = blockIdx.x;
    int batch = blk & 7;
    int win = (batch << 6) | (blk >> 3);
    int b = batch;
    int tid = threadIdx.x, ln = tid & 63, wv = tid >> 6;
    int wh = wv >> 2, rwv = wv & 3;
    int fm = ln & 15, g = ln >> 4, fq = g * 8;

    int myreg = topk[win * 4 + rwv];
    float gw = gwt[win * 4 + rwv];
    float sg = SCALE * gw;
    size_t qbase = (size_t)win * 49 * 256;
    size_t kbase = (size_t)(b * 64 + myreg) * 49 * 256;
    if (ln == 0 && wh == 0) regs_s[rwv] = myreg;

    // ---- phase 1: QK^T (wave = half x region) ----
    int arow[2];
#pragma unroll
    for (int mi = 0; mi < 2; ++mi) {
        int w = wh * 32 + mi * 16 + fm;
        arow[mi] = (w < 49) ? w : 48;
    }

    f32x4 acc[2][4];
#pragma unroll
    for (int i = 0; i < 2; ++i)
#pragma unroll
        for (int j = 0; j < 4; ++j) acc[i][j] = (f32x4){0.f, 0.f, 0.f, 0.f};

#pragma unroll 2
    for (int kc = 0; kc < 256; kc += 32) {
        short8 ah[2], al[2], bh[4], bl[4];
#pragma unroll
        for (int mi = 0; mi < 2; ++mi)
            load_unpack8(&Qp[qbase + (size_t)arow[mi] * 256 + kc + fq], ah[mi], al[mi]);
#pragma unroll
        for (int ni = 0; ni < 4; ++ni) {
            int tok = ni * 16 + fm;
            int trow = (tok < 49) ? tok : 48;
            load_unpack8(&Kp[kbase + (size_t)trow * 256 + kc + fq], bh[ni], bl[ni]);
        }
#pragma unroll
        for (int mi = 0; mi < 2; ++mi)
#pragma unroll
            for (int ni = 0; ni < 4; ++ni) {
                acc[mi][ni] = __builtin_amdgcn_mfma_f32_16x16x32_bf16(ah[mi], bh[ni], acc[mi][ni], 0, 0, 0);
                acc[mi][ni] = __builtin_amdgcn_mfma_f32_16x16x32_bf16(al[mi], bh[ni], acc[mi][ni], 0, 0, 0);
                acc[mi][ni] = __builtin_amdgcn_mfma_f32_16x16x32_bf16(ah[mi], bl[ni], acc[mi][ni], 0, 0, 0);
            }
    }

#pragma unroll
    for (int mi = 0; mi < 2; ++mi)
#pragma unroll
        for (int ni = 0; ni < 4; ++ni) acc[mi][ni] *= sg;

    // ---- softmax (block-wide: 8 waves, 64 rows, 4 region-columns) ----
    float rmax[2][4];
#pragma unroll
    for (int mi = 0; mi < 2; ++mi)
#pragma unroll
        for (int r = 0; r < 4; ++r) rmax[mi][r] = -3.0e38f;
#pragma unroll
    for (int mi = 0; mi < 2; ++mi)
#pragma unroll
        for (int ni = 0; ni < 4; ++ni) {
            if (ni * 16 + fm < 49) {
#pragma unroll
                for (int r = 0; r < 4; ++r)
                    rmax[mi][r] = fmaxf(rmax[mi][r], acc[mi][ni][r]);
            }
        }
#pragma unroll
    for (int off = 1; off < 16; off <<= 1)
#pragma unroll
        for (int mi = 0; mi < 2; ++mi)
#pragma unroll
            for (int r = 0; r < 4; ++r)
                rmax[mi][r] = fmaxf(rmax[mi][r], __shfl_xor(rmax[mi][r], off, 64));
    if (fm == 0) {
#pragma unroll
        for (int mi = 0; mi < 2; ++mi)
#pragma unroll
            for (int r = 0; r < 4; ++r)
                redm[wv][mi * 16 + g * 4 + r] = rmax[mi][r];
    }
    __syncthreads();
    if (tid < 64) {
        int hh = tid >> 5, rb = tid & 31;
        gmax[tid] = fmaxf(fmaxf(redm[hh * 4 + 0][rb], redm[hh * 4 + 1][rb]),
                          fmaxf(redm[hh * 4 + 2][rb], redm[hh * 4 + 3][rb]));
    }
    __syncthreads();

    float gm[2][4];
#pragma unroll
    for (int mi = 0; mi < 2; ++mi)
#pragma unroll
        for (int r = 0; r < 4; ++r) gm[mi][r] = gmax[wh * 32 + mi * 16 + g * 4 + r];
    float rsum[2][4];
#pragma unroll
    for (int mi = 0; mi < 2; ++mi)
#pragma unroll
        for (int r = 0; r < 4; ++r) rsum[mi][r] = 0.f;
#pragma unroll
    for (int mi = 0; mi < 2; ++mi)
#pragma unroll
        for (int ni = 0; ni < 4; ++ni) {
            bool valid = (ni * 16 + fm) < 49;
#pragma unroll
            for (int r = 0; r < 4; ++r) {
                float e = valid ? __expf(acc[mi][ni][r] - gm[mi][r]) : 0.f;
                acc[mi][ni][r] = e;
                rsum[mi][r] += e;
            }
        }
#pragma unroll
    for (int off = 1; off < 16; off <<= 1)
#pragma unroll
        for (int mi = 0; mi < 2; ++mi)
#pragma unroll
            for (int r = 0; r < 4; ++r)
                rsum[mi][r] += __shfl_xor(rsum[mi][r], off, 64);
    if (fm == 0) {
#pragma unroll
        for (int mi = 0; mi < 2; ++mi)
#pragma unroll
            for (int r = 0; r < 4; ++r)
                reds[wv][mi * 16 + g * 4 + r] = rsum[mi][r];
    }
    __syncthreads();
    if (tid < 64) {
        int hh = tid >> 5, rb = tid & 31;
        ginv[tid] = 1.0f / (reds[hh * 4 + 0][rb] + reds[hh * 4 + 1][rb] +
                            reds[hh * 4 + 2][rb] + reds[hh * 4 + 3][rb]);
    }
    __syncthreads();

    // ---- packed P into LDS (rows >=49 get zeros) ----
#pragma unroll
    for (int mi = 0; mi < 2; ++mi) {
#pragma unroll
        for (int r = 0; r < 4; ++r) {
            int rowb = mi * 16 + g * 4 + r;
            int w = wh * 32 + rowb;
            float giv = (w < 49) ? ginv[w] * gw : 0.f;
#pragma unroll
            for (int ni = 0; ni < 4; ++ni) {
                float p = acc[mi][ni][r] * giv;
                Ps[w][rwv * 64 + ni * 16 + fm] = pack2(p);
            }
        }
    }

    // ---- prefetch ATTp RMW values (latency hides under barrier + PV) ----
    int ncol = rwv * 64;
    unsigned int attv[4][2][4];
#pragma unroll
    for (int ni = 0; ni < 4; ++ni) {
        int c = ncol + ni * 16 + fm;
#pragma unroll
        for (int mi = 0; mi < 2; ++mi) {
#pragma unroll
            for (int rr = 0; rr < 4; ++rr) {
                int w = wh * 32 + mi * 16 + g * 4 + rr;
                attv[ni][mi][rr] = (w < 49) ? ATTp[((size_t)win * 49 + w) * 256 + c] : 0u;
            }
        }
    }
    __syncthreads();

    // ---- phase 2: PV (wave = half x 64-col strip) ----
    f32x4 oacc[2][4];
#pragma unroll
    for (int i = 0; i < 2; ++i)
#pragma unroll
        for (int j = 0; j < 4; ++j) oacc[i][j] = (f32x4){0.f, 0.f, 0.f, 0.f};

#pragma unroll 2
    for (int r = 0; r < 4; ++r) {
        int reg = regs_s[r];
        size_t vbase = (size_t)(b * 64 + reg) * 16384;
#pragma unroll
        for (int half = 0; half < 2; ++half) {
            int kc = r * 64 + half * 32;
            int tokoff = half * 32;
            short8 ah[2], al[2], bh[4], bl[4];
#pragma unroll
            for (int mi = 0; mi < 2; ++mi) {
                const unsigned int* p = &Ps[wh * 32 + mi * 16 + fm][kc + fq];
                unpack_u4(*(const uint4*)p, *(const uint4*)(p + 4), ah[mi], al[mi]);
            }
#pragma unroll
            for (int ni = 0; ni < 4; ++ni)
                load_unpack8(&Vtp[vbase + (size_t)(ncol + ni * 16 + fm) * 64 + tokoff + fq], bh[ni], bl[ni]);
#pragma unroll
            for (int mi = 0; mi < 2; ++mi)
#pragma unroll
                for (int ni = 0; ni < 4; ++ni) {
                    oacc[mi][ni] = __builtin_amdgcn_mfma_f32_16x16x32_bf16(ah[mi], bh[ni], oacc[mi][ni], 0, 0, 0);
                    oacc[mi][ni] = __builtin_amdgcn_mfma_f32_16x16x32_bf16(al[mi], bh[ni], oacc[mi][ni], 0, 0, 0);
                    oacc[mi][ni] = __builtin_amdgcn_mfma_f32_16x16x32_bf16(ah[mi], bl[ni], oacc[mi][ni], 0, 0, 0);
                }
        }
    }

    // ---- epilogue: add prefetched dwconv values, repack, store ----
#pragma unroll
    for (int ni = 0; ni < 4; ++ni) {
        int c = ncol + ni * 16 + fm;
#pragma unroll
        for (int mi = 0; mi < 2; ++mi) {
#pragma unroll
            for (int rr = 0; rr < 4; ++rr) {
                int w = wh * 32 + mi * 16 + g * 4 + rr;
                if (w < 49) {
                    size_t i = ((size_t)win * 49 + w) * 256 + c;
                    ATTp[i] = pack2(oacc[mi][ni][rr] + unpack_f(attv[ni][mi][rr]));
                }
            }
        }
    }
}

// ---------------------------------------------------------------------------
// K3: proj GEMM, split-bf16 MFMA. A = packed ATT staged into padded LDS.
__global__ __launch_bounds__(256) void k_mm_proj(
    const unsigned int* __restrict__ Ap,
    const unsigned short* __restrict__ whi, const unsigned short* __restrict__ wlo,
    const float* __restrict__ bp, float* __restrict__ out) {
    __shared__ __align__(16) unsigned int As[128 * 36];
    __shared__ __align__(16) unsigned short Bh[4096];
    __shared__ __align__(16) unsigned short Bl[4096];
    int tid = threadIdx.x;
    int ln = tid & 63, wv = tid >> 6;
    int m0 = blockIdx.y * 128, n0 = blockIdx.x * 128;
    int mrow = (wv >> 1) * 64, ncol = (wv & 1) * 64;

    int lrow = ln >> 2, lseg = (ln & 3) * 8;
    const unsigned short* gB0 = whi + (size_t)(n0 + wv * 32 + lrow) * 256 + lseg;
    const unsigned short* gB1 = gB0 + 16 * 256;
    const unsigned short* gBl0 = wlo + (size_t)(n0 + wv * 32 + lrow) * 256 + lseg;
    const unsigned short* gBl1 = gBl0 + 16 * 256;
    unsigned short* lB0 = &Bh[(wv * 32) * 32];
    unsigned short* lB1 = &Bh[(wv * 32 + 16) * 32];
    unsigned short* lBl0 = &Bl[(wv * 32) * 32];
    unsigned short* lBl1 = &Bl[(wv * 32 + 16) * 32];

    int arow = ln >> 3, akk = (ln & 7) * 4;
    int fm = ln & 15, fq = (ln >> 4) * 8;
    f32x4 acc[4][4];
#pragma unroll
    for (int i = 0; i < 4; ++i)
#pragma unroll
        for (int j = 0; j < 4; ++j) acc[i][j] = (f32x4){0.f, 0.f, 0.f, 0.f};

#pragma unroll 1
    for (int kc = 0; kc < 8; ++kc) {
        if (kc) __syncthreads();
        gload16(gB0, lB0); gload16(gB1, lB1);
        gload16(gBl0, lBl0); gload16(gBl1, lBl1);
        gB0 += 32; gB1 += 32; gBl0 += 32; gBl1 += 32;
#pragma unroll
        for (int it = 0; it < 4; ++it) {
            int row = wv * 32 + it * 8 + arow;
            uint4 v = *(const uint4*)&Ap[(size_t)(m0 + row) * 256 + kc * 32 + akk];
            *(uint4*)&As[row * 36 + akk] = v;
        }
        __syncthreads();

        short8 ah[4], al[4], bh[4], xx[4];
#pragma unroll
        for (int mi = 0; mi < 4; ++mi) {
            const unsigned int* p = &As[(mrow + mi * 16 + fm) * 36 + fq];
            unpack_u4(*(const uint4*)p, *(const uint4*)(p + 4), ah[mi], al[mi]);
        }
#pragma unroll
        for (int ni = 0; ni < 4; ++ni)
            bh[ni] = *(const short8*)&Bh[(ncol + ni * 16 + fm) * 32 + fq];
#pragma unroll
        for (int mi = 0; mi < 4; ++mi)
#pragma unroll
            for (int ni = 0; ni < 4; ++ni)
                acc[mi][ni] = __builtin_amdgcn_mfma_f32_16x16x32_bf16(ah[mi], bh[ni], acc[mi][ni], 0, 0, 0);
#pragma unroll
        for (int mi = 0; mi < 4; ++mi)
#pragma unroll
            for (int ni = 0; ni < 4; ++ni)
                acc[mi][ni] = __builtin_amdgcn_mfma_f32_16x16x32_bf16(al[mi], bh[ni], acc[mi][ni], 0, 0, 0);
#pragma unroll
        for (int ni = 0; ni < 4; ++ni)
            xx[ni] = *(const short8*)&Bl[(ncol + ni * 16 + fm) * 32 + fq];
#pragma unroll
        for (int mi = 0; mi < 4; ++mi)
#pragma unroll
            for (int ni = 0; ni < 4; ++ni)
                acc[mi][ni] = __builtin_amdgcn_mfma_f32_16x16x32_bf16(ah[mi], xx[ni], acc[mi][ni], 0, 0, 0);
    }

    int qrow = (ln >> 4) * 4;
#pragma unroll
    for (int mi = 0; mi < 4; ++mi) {
#pragma unroll
        for (int r = 0; r < 4; ++r) {
            int m = m0 + mrow + mi * 16 + qrow + r;
            size_t orow = (size_t)token_row_addr(m);
#pragma unroll
            for (int ni = 0; ni < 4; ++ni) {
                int col = n0 + ncol + ni * 16 + fm;
                out[orow * 256 + col] = acc[mi][ni][r] + bp[col];
            }
        }
    }
}

// ---------------------------------------------------------------------------
extern "C" void kernel_launch(void* const* d_in, const int* in_sizes, int n_in,
                              void* d_out, int out_size, void* d_ws, size_t ws_size,
                              hipStream_t stream) {
    const float* x    = (const float*)d_in[0];
    const float* wqkv = (const float*)d_in[1];
    const float* bqkv = (const float*)d_in[2];
    const float* wg1  = (const float*)d_in[3];
    const float* bg1  = (const float*)d_in[4];
    const float* wg2  = (const float*)d_in[5];
    const float* bg2  = (const float*)d_in[6];
    const float* dwk  = (const float*)d_in[7];
    const float* dwb  = (const float*)d_in[8];
    const float* wp   = (const float*)d_in[9];
    const float* bp   = (const float*)d_in[10];
    float* out = (float*)d_out;

    const size_t NTOT = (size_t)25088 * 256;     // 6,422,528
    const size_t VTSZ = (size_t)512 * 256 * 64;  // 8,388,608
    unsigned int* Qp  = (unsigned int*)d_ws;
    unsigned int* Kp  = Qp + NTOT;
    unsigned int* Vp  = Kp + NTOT;
    unsigned int* Vtp = Vp + NTOT;
    unsigned int* Pp  = Vtp + VTSZ;              // unused (kept for layout)
    unsigned short* XH = (unsigned short*)(Pp + VTSZ);  // x bf16 hi; later ATTp
    unsigned short* XL = XH + NTOT;                     // x bf16 lo
    unsigned int* ATTp = (unsigned int*)XH;             // alias (x dead after qkv)
    unsigned short* WQH = XL + NTOT;
    unsigned short* WQL = WQH + 768 * 256;
    unsigned short* WPH = WQL + 768 * 256;
    unsigned short* WPL = WPH + 256 * 256;
    float* QKVR = (float*)(WPL + 256 * 256);
    float* SIG  = QKVR + 512 * 768;
    float* GWT  = SIG + 1024;
    int*   TOPK = (int*)(GWT + 2048);

    hipLaunchKernelGGL(k_cvt_x, dim3(25088), dim3(256), 0, stream, x, XH, XL);
    hipLaunchKernelGGL(k_cvt_w, dim3(768), dim3(256), 0, stream, wqkv, 768, WQH, WQL);
    hipLaunchKernelGGL(k_cvt_w, dim3(256), dim3(256), 0, stream, wp, 256, WPH, WPL);
    hipLaunchKernelGGL(k_region_fused, dim3(512), dim3(256), 0, stream,
                       x, wqkv, bqkv, wg1, bg1, wg2, bg2, QKVR, SIG);
    hipLaunchKernelGGL(k_topk_gauss, dim3(512), dim3(64), 0, stream, QKVR, SIG, TOPK, GWT);
    hipLaunchKernelGGL(k_mm_qkv, dim3(6, 196), dim3(256), 0, stream,
                       XH, XL, WQH, WQL, bqkv, Qp, Kp, Vp);
    hipLaunchKernelGGL(k_transpose_v, dim3(512), dim3(256), 0, stream,
                       Vp, Vtp, dwk, dwb, ATTp);
    hipLaunchKernelGGL(k_attn, dim3(512), dim3(512), 0, stream,
                       Qp, Kp, Vtp, TOPK, GWT, ATTp);
    hipLaunchKernelGGL(k_mm_proj, dim3(2, 196), dim3(256), 0, stream,
                       ATTp, WPH, WPL, bp, out);
}

// Round 8
// 332.471 us; speedup vs baseline: 1.0356x; 1.0356x over previous
//
#include <hip/hip_runtime.h>
#include <math.h>

#define SCALE 0.17677669529663687f  /* (256/8)^-0.5 */

typedef short short8 __attribute__((ext_vector_type(8)));
typedef float f32x4 __attribute__((ext_vector_type(4)));

// ---------------------------------------------------------------------------
__device__ __forceinline__ int token_row_addr(int m) {
    int b = m / 3136;
    int rem = m - b * 3136;
    int s = rem / 49;
    int tok = rem - s * 49;
    int h = (s >> 3) * 7 + tok / 7;
    int w = (s & 7) * 7 + (tok % 7);
    return (b * 56 + h) * 56 + w;
}

__device__ __forceinline__ void split2(float x, unsigned short& h, unsigned short& l) {
    unsigned int u = __float_as_uint(x);
    h = (unsigned short)(u >> 16);
    float hf = __uint_as_float(u & 0xFFFF0000u);
    l = (unsigned short)(__float_as_uint(x - hf) >> 16);
}

__device__ __forceinline__ unsigned int pack2(float x) {
    unsigned short h, l;
    split2(x, h, l);
    return ((unsigned int)h << 16) | l;
}

__device__ __forceinline__ float b2f(unsigned short u) {
    return __uint_as_float(((unsigned int)u) << 16);
}

__device__ __forceinline__ float unpack_f(unsigned int u) {
    return b2f((unsigned short)(u >> 16)) + b2f((unsigned short)(u & 0xFFFFu));
}

__device__ __forceinline__ void unpack_u4(uint4 a, uint4 b, short8& h, short8& l) {
    h[0] = (short)(a.x >> 16); l[0] = (short)(a.x & 0xFFFFu);
    h[1] = (short)(a.y >> 16); l[1] = (short)(a.y & 0xFFFFu);
    h[2] = (short)(a.z >> 16); l[2] = (short)(a.z & 0xFFFFu);
    h[3] = (short)(a.w >> 16); l[3] = (short)(a.w & 0xFFFFu);
    h[4] = (short)(b.x >> 16); l[4] = (short)(b.x & 0xFFFFu);
    h[5] = (short)(b.y >> 16); l[5] = (short)(b.y & 0xFFFFu);
    h[6] = (short)(b.z >> 16); l[6] = (short)(b.z & 0xFFFFu);
    h[7] = (short)(b.w >> 16); l[7] = (short)(b.w & 0xFFFFu);
}

__device__ __forceinline__ void load_unpack8(const unsigned int* g, short8& h, short8& l) {
    uint4 a = *(const uint4*)g;
    uint4 b = *(const uint4*)(g + 4);
    unpack_u4(a, b, h, l);
}

__device__ __forceinline__ void gload16(const unsigned short* g, unsigned short* l) {
    __builtin_amdgcn_global_load_lds(
        (const __attribute__((address_space(1))) unsigned int*)g,
        (__attribute__((address_space(3))) unsigned int*)l, 16, 0, 0);
}

// ---------------------------------------------------------------------------
// converter (weights only; x conversion fused into k_region_fused)
__global__ void k_cvt_w(const float* __restrict__ w, int ncols,
                        unsigned short* __restrict__ whi, unsigned short* __restrict__ wlo) {
    int n = blockIdx.x;
    int k = threadIdx.x;
    float v = w[(size_t)k * ncols + n];
    unsigned short h, l;
    split2(v, h, l);
    whi[(size_t)n * 256 + k] = h;
    wlo[(size_t)n * 256 + k] = l;
}

// ---------------------------------------------------------------------------
// K0: fused region path: x->bf16 split store + mean -> qkv_r -> gating.
// grid 512 (= b*64+s), block 256. The token loop touches every x element in
// exactly the (win,tok,c) order XH/XL need, so the cvt_x kernel is folded in
// here (saves a second full 103 MB read of x).
__global__ void k_region_fused(const float* __restrict__ x, const float* __restrict__ wqkv,
                               const float* __restrict__ bqkv, const float* __restrict__ wg1,
                               const float* __restrict__ bg1, const float* __restrict__ wg2,
                               const float* __restrict__ bg2, float* __restrict__ qkvr,
                               float* __restrict__ sig,
                               unsigned short* __restrict__ xhi,
                               unsigned short* __restrict__ xlo) {
    __shared__ float xs[256];
    __shared__ float qbuf[256];
    __shared__ float hs[64];
    int blk = blockIdx.x;
    int b = blk >> 6, s = blk & 63;
    int t = threadIdx.x;
    int hy0 = (s >> 3) * 7, wx0 = (s & 7) * 7;
    const float* xb = x + ((size_t)b * 56 * 56) * 256 + t;
    size_t mbase = (size_t)blk * 49 * 256 + t;
    float sum = 0.f;
#pragma unroll 1
    for (int tt = 0; tt < 49; ++tt) {
        int h = hy0 + tt / 7, w = wx0 + (tt % 7);
        float v = xb[(size_t)(h * 56 + w) * 256];
        sum += v;
        unsigned short hi, lo;
        split2(v, hi, lo);
        xhi[mbase + (size_t)tt * 256] = hi;
        xlo[mbase + (size_t)tt * 256] = lo;
    }
    xs[t] = sum * (1.0f / 49.0f);
    __syncthreads();

    float a0 = 0.f, a1 = 0.f, a2 = 0.f;
#pragma unroll 4
    for (int k = 0; k < 256; ++k) {
        float xv = xs[k];
        const float* wrow = wqkv + (size_t)k * 768;
        a0 += xv * wrow[t];
        a1 += xv * wrow[t + 256];
        a2 += xv * wrow[t + 512];
    }
    float q = a0 + bqkv[t];
    qbuf[t] = q;
    float* o = qkvr + (size_t)blk * 768;
    o[t]       = q;
    o[t + 256] = a1 + bqkv[t + 256];
    o[t + 512] = a2 + bqkv[t + 512];
    __syncthreads();

    if (t < 64) {
        float acc = bg1[t];
#pragma unroll 4
        for (int k = 0; k < 256; ++k) acc += qbuf[k] * wg1[(size_t)k * 64 + t];
        hs[t] = fmaxf(acc, 0.f);
    }
    __syncthreads();
    if (t < 2) {
        float gp = bg2[t];
#pragma unroll 1
        for (int m = 0; m < 64; ++m) gp += hs[m] * wg2[m * 2 + t];
        float sp = fmaxf(gp, 0.f) + log1pf(expf(-fabsf(gp)));
        sig[blk * 2 + t] = sp + 0.5f;
    }
}

__global__ void k_topk_gauss(const float* __restrict__ qkvr, const float* __restrict__ sig,
                             int* __restrict__ topk, float* __restrict__ gwt) {
    __shared__ float A[64];
    __shared__ float G[64];
    __shared__ int idxs[4];
    __shared__ float gsum_s;
    int blk = blockIdx.x;
    int b = blk >> 6, s = blk & 63;
    int z = threadIdx.x;
    const float* qr = qkvr + (size_t)blk * 768;
    const float* kr = qkvr + (size_t)(b * 64 + z) * 768 + 256;
    float acc = 0.f;
#pragma unroll 4
    for (int k = 0; k < 256; k += 4) {
        float4 q4 = *(const float4*)(qr + k);
        float4 k4 = *(const float4*)(kr + k);
        acc += q4.x * k4.x + q4.y * k4.y + q4.z * k4.z + q4.w * k4.w;
    }
    A[z] = acc * SCALE;
    float s0 = sig[blk * 2 + 0], s1 = sig[blk * 2 + 1];
    float dx = (float)((z & 7) - (s & 7));
    float dy = (float)((z >> 3) - (s >> 3));
    float t0 = dx / s0, t1 = dy / s1;
    float zz = t0 * t0 + t1 * t1;
    G[z] = expf(-0.5f * zz);
    __syncthreads();
    if (z == 0) {
        float gs = 0.f;
        for (int m = 0; m < 64; ++m) gs += G[m];
        gsum_s = gs + 1e-6f;
        for (int it = 0; it < 4; ++it) {
            int best = 0;
            float bv = A[0];
            for (int m = 1; m < 64; ++m) {
                if (A[m] > bv) { bv = A[m]; best = m; }
            }
            idxs[it] = best;
            A[best] = -3.0e38f;
        }
    }
    __syncthreads();
    if (z < 4) {
        int id = idxs[z];
        topk[blk * 4 + z] = id;
        gwt[blk * 4 + z] = G[id] / gsum_s;
    }
}

// ---------------------------------------------------------------------------
// K1: qkv GEMM, split-bf16 MFMA, 128x128 tile, BK=32. grid (6, 196).
__global__ __launch_bounds__(256) void k_mm_qkv(
    const unsigned short* __restrict__ xhi, const unsigned short* __restrict__ xlo,
    const unsigned short* __restrict__ whi, const unsigned short* __restrict__ wlo,
    const float* __restrict__ bqkv,
    unsigned int* __restrict__ Qp, unsigned int* __restrict__ Kp,
    unsigned int* __restrict__ Vp) {
    __shared__ __align__(16) unsigned short Ah[4096];
    __shared__ __align__(16) unsigned short Al[4096];
    __shared__ __align__(16) unsigned short Bh[4096];
    __shared__ __align__(16) unsigned short Bl[4096];
    int tid = threadIdx.x;
    int ln = tid & 63, wv = tid >> 6;
    int m0 = blockIdx.y * 128, n0 = blockIdx.x * 128;
    int mrow = (wv >> 1) * 64, ncol = (wv & 1) * 64;

    int lrow = ln >> 2, lseg = (ln & 3) * 8;
    const unsigned short* gA0 = xhi + (size_t)(m0 + wv * 32 + lrow) * 256 + lseg;
    const unsigned short* gA1 = gA0 + 16 * 256;
    const unsigned short* gAl0 = xlo + (size_t)(m0 + wv * 32 + lrow) * 256 + lseg;
    const unsigned short* gAl1 = gAl0 + 16 * 256;
    const unsigned short* gB0 = whi + (size_t)(n0 + wv * 32 + lrow) * 256 + lseg;
    const unsigned short* gB1 = gB0 + 16 * 256;
    const unsigned short* gBl0 = wlo + (size_t)(n0 + wv * 32 + lrow) * 256 + lseg;
    const unsigned short* gBl1 = gBl0 + 16 * 256;
    unsigned short* lA0 = &Ah[(wv * 32) * 32];
    unsigned short* lA1 = &Ah[(wv * 32 + 16) * 32];
    unsigned short* lAl0 = &Al[(wv * 32) * 32];
    unsigned short* lAl1 = &Al[(wv * 32 + 16) * 32];
    unsigned short* lB0 = &Bh[(wv * 32) * 32];
    unsigned short* lB1 = &Bh[(wv * 32 + 16) * 32];
    unsigned short* lBl0 = &Bl[(wv * 32) * 32];
    unsigned short* lBl1 = &Bl[(wv * 32 + 16) * 32];

    int fm = ln & 15, fq = (ln >> 4) * 8;
    f32x4 acc[4][4];
#pragma unroll
    for (int i = 0; i < 4; ++i)
#pragma unroll
        for (int j = 0; j < 4; ++j) acc[i][j] = (f32x4){0.f, 0.f, 0.f, 0.f};

#pragma unroll 1
    for (int kc = 0; kc < 8; ++kc) {
        if (kc) __syncthreads();
        gload16(gA0, lA0); gload16(gA1, lA1);
        gload16(gAl0, lAl0); gload16(gAl1, lAl1);
        gload16(gB0, lB0); gload16(gB1, lB1);
        gload16(gBl0, lBl0); gload16(gBl1, lBl1);
        gA0 += 32; gA1 += 32; gAl0 += 32; gAl1 += 32;
        gB0 += 32; gB1 += 32; gBl0 += 32; gBl1 += 32;
        __syncthreads();

        short8 ah[4], bh[4], xx[4];
#pragma unroll
        for (int mi = 0; mi < 4; ++mi)
            ah[mi] = *(const short8*)&Ah[(mrow + mi * 16 + fm) * 32 + fq];
#pragma unroll
        for (int ni = 0; ni < 4; ++ni)
            bh[ni] = *(const short8*)&Bh[(ncol + ni * 16 + fm) * 32 + fq];
#pragma unroll
        for (int mi = 0; mi < 4; ++mi)
#pragma unroll
            for (int ni = 0; ni < 4; ++ni)
                acc[mi][ni] = __builtin_amdgcn_mfma_f32_16x16x32_bf16(ah[mi], bh[ni], acc[mi][ni], 0, 0, 0);
#pragma unroll
        for (int mi = 0; mi < 4; ++mi)
            xx[mi] = *(const short8*)&Al[(mrow + mi * 16 + fm) * 32 + fq];
#pragma unroll
        for (int mi = 0; mi < 4; ++mi)
#pragma unroll
            for (int ni = 0; ni < 4; ++ni)
                acc[mi][ni] = __builtin_amdgcn_mfma_f32_16x16x32_bf16(xx[mi], bh[ni], acc[mi][ni], 0, 0, 0);
#pragma unroll
        for (int ni = 0; ni < 4; ++ni)
            xx[ni] = *(const short8*)&Bl[(ncol + ni * 16 + fm) * 32 + fq];
#pragma unroll
        for (int mi = 0; mi < 4; ++mi)
#pragma unroll
            for (int ni = 0; ni < 4; ++ni)
                acc[mi][ni] = __builtin_amdgcn_mfma_f32_16x16x32_bf16(ah[mi], xx[ni], acc[mi][ni], 0, 0, 0);
    }

    int nb = n0 >> 7;
    unsigned int* dst = (nb < 2) ? Qp : (nb < 4) ? Kp : Vp;
    int qrow = (ln >> 4) * 4;
#pragma unroll
    for (int ni = 0; ni < 4; ++ni) {
        int col = (n0 & 255) + ncol + ni * 16 + fm;
        float bias = bqkv[n0 + ncol + ni * 16 + fm];
#pragma unroll
        for (int mi = 0; mi < 4; ++mi) {
#pragma unroll
            for (int r = 0; r < 4; ++r) {
                int m = m0 + mrow + mi * 16 + qrow + r;
                dst[(size_t)m * 256 + col] = pack2(acc[mi][ni][r] + bias);
            }
        }
    }
}

// ---------------------------------------------------------------------------
// K1b: transpose Vp -> Vtp[win][c][64] packed (pads zeroed) AND fused dwconv
// -> ATTp initial value. grid 512, block 256.
__global__ __launch_bounds__(256) void k_transpose_v(
    const unsigned int* __restrict__ Vp, unsigned int* __restrict__ Vtp,
    const float* __restrict__ dwk, const float* __restrict__ dwb,
    unsigned int* __restrict__ ATTp) {
    __shared__ unsigned int T[49][257];
    int win = blockIdx.x;
    int tid = threadIdx.x;
#pragma unroll 1
    for (int i = tid; i < 49 * 64; i += 256) {
        int tok = i >> 6, cq = (i & 63) * 4;
        uint4 v = *(const uint4*)&Vp[((size_t)win * 49 + tok) * 256 + cq];
        T[tok][cq + 0] = v.x;
        T[tok][cq + 1] = v.y;
        T[tok][cq + 2] = v.z;
        T[tok][cq + 3] = v.w;
    }
    __syncthreads();
#pragma unroll 1
    for (int it = 0; it < 8; ++it) {
        int item = tid + it * 256;
        int c = item >> 3, t8 = (item & 7) * 8;
        uint4 o0, o1;
        o0.x = (t8 + 0 < 49) ? T[t8 + 0][c] : 0u;
        o0.y = (t8 + 1 < 49) ? T[t8 + 1][c] : 0u;
        o0.z = (t8 + 2 < 49) ? T[t8 + 2][c] : 0u;
        o0.w = (t8 + 3 < 49) ? T[t8 + 3][c] : 0u;
        o1.x = (t8 + 4 < 49) ? T[t8 + 4][c] : 0u;
        o1.y = (t8 + 5 < 49) ? T[t8 + 5][c] : 0u;
        o1.z = (t8 + 6 < 49) ? T[t8 + 6][c] : 0u;
        o1.w = (t8 + 7 < 49) ? T[t8 + 7][c] : 0u;
        size_t o = (size_t)win * 16384 + (size_t)c * 64 + t8;
        *(uint4*)&Vtp[o] = o0;
        *(uint4*)&Vtp[o + 4] = o1;
    }

    // fused dwconv: thread tid owns channel c = tid for all 49 tokens.
    {
        int c = tid;
        float dk[9];
#pragma unroll
        for (int t = 0; t < 9; ++t) dk[t] = dwk[(size_t)t * 256 + c];
        float db = dwb[c];
#pragma unroll 1
        for (int py = 0; py < 7; ++py) {
#pragma unroll 1
            for (int px = 0; px < 7; ++px) {
                float vd = db;
#pragma unroll
                for (int dy = 0; dy < 3; ++dy) {
                    int yy = py + dy - 1;
                    if (yy < 0 || yy > 6) continue;   // wave-uniform branch
#pragma unroll
                    for (int dx = 0; dx < 3; ++dx) {
                        int xx = px + dx - 1;
                        if (xx < 0 || xx > 6) continue;  // wave-uniform branch
                        vd += unpack_f(T[yy * 7 + xx][c]) * dk[dy * 3 + dx];
                    }
                }
                int w = py * 7 + px;
                ATTp[((size_t)win * 49 + w) * 256 + c] = pack2(vd);
            }
        }
    }
}

// ---------------------------------------------------------------------------
// K2: FUSED attention: QK^T + softmax + PV + ATTp RMW. grid 1024, block 256.
// (round-6 structure: best measured 80.6 us; the 512-thread merge was neutral
// on FETCH and slower, reverted)
__global__ __launch_bounds__(256) void k_attn(
    const unsigned int* __restrict__ Qp, const unsigned int* __restrict__ Kp,
    const unsigned int* __restrict__ Vtp,
    const int* __restrict__ topk, const float* __restrict__ gwt,
    unsigned int* __restrict__ ATTp) {
    __shared__ __align__(16) unsigned int Ps[32][260];
    __shared__ float redm[4][32];
    __shared__ float reds[4][32];
    __shared__ float gmax[32];
    __shared__ float ginv[32];
    __shared__ int regs_s[4];
    int blk = blockIdx.x;
    int batch = blk & 7, idx = blk >> 3;
    int win = (batch << 6) | (idx >> 1);
    int wh = idx & 1;
    int b = batch;
    int tid = threadIdx.x, ln = tid & 63, wv = tid >> 6;
    int fm = ln & 15, g = ln >> 4, fq = g * 8;

    int myreg = topk[win * 4 + wv];
    float gw = gwt[win * 4 + wv];
    float sg = SCALE * gw;
    size_t qbase = (size_t)win * 49 * 256;
    size_t kbase = (size_t)(b * 64 + myreg) * 49 * 256;
    if (ln == 0) regs_s[wv] = myreg;

    // ---- phase 1: QK^T (wave = region wv) ----
    int arow[2];
#pragma unroll
    for (int mi = 0; mi < 2; ++mi) {
        int w = wh * 32 + mi * 16 + fm;
        arow[mi] = (w < 49) ? w : 48;
    }

    f32x4 acc[2][4];
#pragma unroll
    for (int i = 0; i < 2; ++i)
#pragma unroll
        for (int j = 0; j < 4; ++j) acc[i][j] = (f32x4){0.f, 0.f, 0.f, 0.f};

#pragma unroll 2
    for (int kc = 0; kc < 256; kc += 32) {
        short8 ah[2], al[2], bh[4], bl[4];
#pragma unroll
        for (int mi = 0; mi < 2; ++mi)
            load_unpack8(&Qp[qbase + (size_t)arow[mi] * 256 + kc + fq], ah[mi], al[mi]);
#pragma unroll
        for (int ni = 0; ni < 4; ++ni) {
            int tok = ni * 16 + fm;
            int trow = (tok < 49) ? tok : 48;
            load_unpack8(&Kp[kbase + (size_t)trow * 256 + kc + fq], bh[ni], bl[ni]);
        }
#pragma unroll
        for (int mi = 0; mi < 2; ++mi)
#pragma unroll
            for (int ni = 0; ni < 4; ++ni) {
                acc[mi][ni] = __builtin_amdgcn_mfma_f32_16x16x32_bf16(ah[mi], bh[ni], acc[mi][ni], 0, 0, 0);
                acc[mi][ni] = __builtin_amdgcn_mfma_f32_16x16x32_bf16(al[mi], bh[ni], acc[mi][ni], 0, 0, 0);
                acc[mi][ni] = __builtin_amdgcn_mfma_f32_16x16x32_bf16(ah[mi], bl[ni], acc[mi][ni], 0, 0, 0);
            }
    }

#pragma unroll
    for (int mi = 0; mi < 2; ++mi)
#pragma unroll
        for (int ni = 0; ni < 4; ++ni) acc[mi][ni] *= sg;

    // ---- softmax (block-wide over 4 regions) ----
    float rmax[2][4];
#pragma unroll
    for (int mi = 0; mi < 2; ++mi)
#pragma unroll
        for (int r = 0; r < 4; ++r) rmax[mi][r] = -3.0e38f;
#pragma unroll
    for (int mi = 0; mi < 2; ++mi)
#pragma unroll
        for (int ni = 0; ni < 4; ++ni) {
            if (ni * 16 + fm < 49) {
#pragma unroll
                for (int r = 0; r < 4; ++r)
                    rmax[mi][r] = fmaxf(rmax[mi][r], acc[mi][ni][r]);
            }
        }
#pragma unroll
    for (int off = 1; off < 16; off <<= 1)
#pragma unroll
        for (int mi = 0; mi < 2; ++mi)
#pragma unroll
            for (int r = 0; r < 4; ++r)
                rmax[mi][r] = fmaxf(rmax[mi][r], __shfl_xor(rmax[mi][r], off, 64));
    if (fm == 0) {
#pragma unroll
        for (int mi = 0; mi < 2; ++mi)
#pragma unroll
            for (int r = 0; r < 4; ++r)
                redm[wv][mi * 16 + g * 4 + r] = rmax[mi][r];
    }
    __syncthreads();
    if (tid < 32)
        gmax[tid] = fmaxf(fmaxf(redm[0][tid], redm[1][tid]),
                          fmaxf(redm[2][tid], redm[3][tid]));
    __syncthreads();

    float gm[2][4];
#pragma unroll
    for (int mi = 0; mi < 2; ++mi)
#pragma unroll
        for (int r = 0; r < 4; ++r) gm[mi][r] = gmax[mi * 16 + g * 4 + r];
    float rsum[2][4];
#pragma unroll
    for (int mi = 0; mi < 2; ++mi)
#pragma unroll
        for (int r = 0; r < 4; ++r) rsum[mi][r] = 0.f;
#pragma unroll
    for (int mi = 0; mi < 2; ++mi)
#pragma unroll
        for (int ni = 0; ni < 4; ++ni) {
            bool valid = (ni * 16 + fm) < 49;
#pragma unroll
            for (int r = 0; r < 4; ++r) {
                float e = valid ? __expf(acc[mi][ni][r] - gm[mi][r]) : 0.f;
                acc[mi][ni][r] = e;
                rsum[mi][r] += e;
            }
        }
#pragma unroll
    for (int off = 1; off < 16; off <<= 1)
#pragma unroll
        for (int mi = 0; mi < 2; ++mi)
#pragma unroll
            for (int r = 0; r < 4; ++r)
                rsum[mi][r] += __shfl_xor(rsum[mi][r], off, 64);
    if (fm == 0) {
#pragma unroll
        for (int mi = 0; mi < 2; ++mi)
#pragma unroll
            for (int r = 0; r < 4; ++r)
                reds[wv][mi * 16 + g * 4 + r] = rsum[mi][r];
    }
    __syncthreads();
    if (tid < 32)
        ginv[tid] = 1.0f / (reds[0][tid] + reds[1][tid] + reds[2][tid] + reds[3][tid]);
    __syncthreads();

    // ---- packed P into LDS (rows >=49 get zeros) ----
#pragma unroll
    for (int mi = 0; mi < 2; ++mi) {
#pragma unroll
        for (int r = 0; r < 4; ++r) {
            int rowb = mi * 16 + g * 4 + r;
            int w = wh * 32 + rowb;
            float giv = (w < 49) ? ginv[rowb] * gw : 0.f;
#pragma unroll
            for (int ni = 0; ni < 4; ++ni) {
                float p = acc[mi][ni][r] * giv;
                Ps[rowb][wv * 64 + ni * 16 + fm] = pack2(p);
            }
        }
    }

    // ---- prefetch ATTp RMW values (latency hides under barrier + PV) ----
    int ncol = wv * 64;
    unsigned int attv[4][2][4];
#pragma unroll
    for (int ni = 0; ni < 4; ++ni) {
        int c = ncol + ni * 16 + fm;
#pragma unroll
        for (int mi = 0; mi < 2; ++mi) {
#pragma unroll
            for (int rr = 0; rr < 4; ++rr) {
                int w = wh * 32 + mi * 16 + g * 4 + rr;
                attv[ni][mi][rr] = (w < 49) ? ATTp[((size_t)win * 49 + w) * 256 + c] : 0u;
            }
        }
    }
    __syncthreads();

    // ---- phase 2: PV (wave = 64-col strip) ----
    f32x4 oacc[2][4];
#pragma unroll
    for (int i = 0; i < 2; ++i)
#pragma unroll
        for (int j = 0; j < 4; ++j) oacc[i][j] = (f32x4){0.f, 0.f, 0.f, 0.f};

#pragma unroll 2
    for (int r = 0; r < 4; ++r) {
        int reg = regs_s[r];
        size_t vbase = (size_t)(b * 64 + reg) * 16384;
#pragma unroll
        for (int half = 0; half < 2; ++half) {
            int kc = r * 64 + half * 32;
            int tokoff = half * 32;
            short8 ah[2], al[2], bh[4], bl[4];
#pragma unroll
            for (int mi = 0; mi < 2; ++mi) {
                const unsigned int* p = &Ps[mi * 16 + fm][kc + fq];
                unpack_u4(*(const uint4*)p, *(const uint4*)(p + 4), ah[mi], al[mi]);
            }
#pragma unroll
            for (int ni = 0; ni < 4; ++ni)
                load_unpack8(&Vtp[vbase + (size_t)(ncol + ni * 16 + fm) * 64 + tokoff + fq], bh[ni], bl[ni]);
#pragma unroll
            for (int mi = 0; mi < 2; ++mi)
#pragma unroll
                for (int ni = 0; ni < 4; ++ni) {
                    oacc[mi][ni] = __builtin_amdgcn_mfma_f32_16x16x32_bf16(ah[mi], bh[ni], oacc[mi][ni], 0, 0, 0);
                    oacc[mi][ni] = __builtin_amdgcn_mfma_f32_16x16x32_bf16(al[mi], bh[ni], oacc[mi][ni], 0, 0, 0);
                    oacc[mi][ni] = __builtin_amdgcn_mfma_f32_16x16x32_bf16(ah[mi], bl[ni], oacc[mi][ni], 0, 0, 0);
                }
        }
    }

    // ---- epilogue: add prefetched dwconv values, repack, store ----
#pragma unroll
    for (int ni = 0; ni < 4; ++ni) {
        int c = ncol + ni * 16 + fm;
#pragma unroll
        for (int mi = 0; mi < 2; ++mi) {
#pragma unroll
            for (int rr = 0; rr < 4; ++rr) {
                int w = wh * 32 + mi * 16 + g * 4 + rr;
                if (w < 49) {
                    size_t i = ((size_t)win * 49 + w) * 256 + c;
                    ATTp[i] = pack2(oacc[mi][ni][rr] + unpack_f(attv[ni][mi][rr]));
                }
            }
        }
    }
}

// ---------------------------------------------------------------------------
// K3: proj GEMM, split-bf16 MFMA. A = packed ATT staged into padded LDS.
__global__ __launch_bounds__(256) void k_mm_proj(
    const unsigned int* __restrict__ Ap,
    const unsigned short* __restrict__ whi, const unsigned short* __restrict__ wlo,
    const float* __restrict__ bp, float* __restrict__ out) {
    __shared__ __align__(16) unsigned int As[128 * 36];
    __shared__ __align__(16) unsigned short Bh[4096];
    __shared__ __align__(16) unsigned short Bl[4096];
    int tid = threadIdx.x;
    int ln = tid & 63, wv = tid >> 6;
    int m0 = blockIdx.y * 128, n0 = blockIdx.x * 128;
    int mrow = (wv >> 1) * 64, ncol = (wv & 1) * 64;

    int lrow = ln >> 2, lseg = (ln & 3) * 8;
    const unsigned short* gB0 = whi + (size_t)(n0 + wv * 32 + lrow) * 256 + lseg;
    const unsigned short* gB1 = gB0 + 16 * 256;
    const unsigned short* gBl0 = wlo + (size_t)(n0 + wv * 32 + lrow) * 256 + lseg;
    const unsigned short* gBl1 = gBl0 + 16 * 256;
    unsigned short* lB0 = &Bh[(wv * 32) * 32];
    unsigned short* lB1 = &Bh[(wv * 32 + 16) * 32];
    unsigned short* lBl0 = &Bl[(wv * 32) * 32];
    unsigned short* lBl1 = &Bl[(wv * 32 + 16) * 32];

    int arow = ln >> 3, akk = (ln & 7) * 4;
    int fm = ln & 15, fq = (ln >> 4) * 8;
    f32x4 acc[4][4];
#pragma unroll
    for (int i = 0; i < 4; ++i)
#pragma unroll
        for (int j = 0; j < 4; ++j) acc[i][j] = (f32x4){0.f, 0.f, 0.f, 0.f};

#pragma unroll 1
    for (int kc = 0; kc < 8; ++kc) {
        if (kc) __syncthreads();
        gload16(gB0, lB0); gload16(gB1, lB1);
        gload16(gBl0, lBl0); gload16(gBl1, lBl1);
        gB0 += 32; gB1 += 32; gBl0 += 32; gBl1 += 32;
#pragma unroll
        for (int it = 0; it < 4; ++it) {
            int row = wv * 32 + it * 8 + arow;
            uint4 v = *(const uint4*)&Ap[(size_t)(m0 + row) * 256 + kc * 32 + akk];
            *(uint4*)&As[row * 36 + akk] = v;
        }
        __syncthreads();

        short8 ah[4], al[4], bh[4], xx[4];
#pragma unroll
        for (int mi = 0; mi < 4; ++mi) {
            const unsigned int* p = &As[(mrow + mi * 16 + fm) * 36 + fq];
            unpack_u4(*(const uint4*)p, *(const uint4*)(p + 4), ah[mi], al[mi]);
        }
#pragma unroll
        for (int ni = 0; ni < 4; ++ni)
            bh[ni] = *(const short8*)&Bh[(ncol + ni * 16 + fm) * 32 + fq];
#pragma unroll
        for (int mi = 0; mi < 4; ++mi)
#pragma unroll
            for (int ni = 0; ni < 4; ++ni)
                acc[mi][ni] = __builtin_amdgcn_mfma_f32_16x16x32_bf16(ah[mi], bh[ni], acc[mi][ni], 0, 0, 0);
#pragma unroll
        for (int mi = 0; mi < 4; ++mi)
#pragma unroll
            for (int ni = 0; ni < 4; ++ni)
                acc[mi][ni] = __builtin_amdgcn_mfma_f32_16x16x32_bf16(al[mi], bh[ni], acc[mi][ni], 0, 0, 0);
#pragma unroll
        for (int ni = 0; ni < 4; ++ni)
            xx[ni] = *(const short8*)&Bl[(ncol + ni * 16 + fm) * 32 + fq];
#pragma unroll
        for (int mi = 0; mi < 4; ++mi)
#pragma unroll
            for (int ni = 0; ni < 4; ++ni)
                acc[mi][ni] = __builtin_amdgcn_mfma_f32_16x16x32_bf16(ah[mi], xx[ni], acc[mi][ni], 0, 0, 0);
    }

    int qrow = (ln >> 4) * 4;
#pragma unroll
    for (int mi = 0; mi < 4; ++mi) {
#pragma unroll
        for (int r = 0; r < 4; ++r) {
            int m = m0 + mrow + mi * 16 + qrow + r;
            size_t orow = (size_t)token_row_addr(m);
#pragma unroll
            for (int ni = 0; ni < 4; ++ni) {
                int col = n0 + ncol + ni * 16 + fm;
                out[orow * 256 + col] = acc[mi][ni][r] + bp[col];
            }
        }
    }
}

// ---------------------------------------------------------------------------
extern "C" void kernel_launch(void* const* d_in, const int* in_sizes, int n_in,
                              void* d_out, int out_size, void* d_ws, size_t ws_size,
                              hipStream_t stream) {
    const float* x    = (const float*)d_in[0];
    const float* wqkv = (const float*)d_in[1];
    const float* bqkv = (const float*)d_in[2];
    const float* wg1  = (const float*)d_in[3];
    const float* bg1  = (const float*)d_in[4];
    const float* wg2  = (const float*)d_in[5];
    const float* bg2  = (const float*)d_in[6];
    const float* dwk  = (const float*)d_in[7];
    const float* dwb  = (const float*)d_in[8];
    const float* wp   = (const float*)d_in[9];
    const float* bp   = (const float*)d_in[10];
    float* out = (float*)d_out;

    const size_t NTOT = (size_t)25088 * 256;     // 6,422,528
    const size_t VTSZ = (size_t)512 * 256 * 64;  // 8,388,608
    unsigned int* Qp  = (unsigned int*)d_ws;
    unsigned int* Kp  = Qp + NTOT;
    unsigned int* Vp  = Kp + NTOT;
    unsigned int* Vtp = Vp + NTOT;
    unsigned int* Pp  = Vtp + VTSZ;              // unused (kept for layout)
    unsigned short* XH = (unsigned short*)(Pp + VTSZ);  // x bf16 hi; later ATTp
    unsigned short* XL = XH + NTOT;                     // x bf16 lo
    unsigned int* ATTp = (unsigned int*)XH;             // alias (x dead after qkv)
    unsigned short* WQH = XL + NTOT;
    unsigned short* WQL = WQH + 768 * 256;
    unsigned short* WPH = WQL + 768 * 256;
    unsigned short* WPL = WPH + 256 * 256;
    float* QKVR = (float*)(WPL + 256 * 256);
    float* SIG  = QKVR + 512 * 768;
    float* GWT  = SIG + 1024;
    int*   TOPK = (int*)(GWT + 2048);

    hipLaunchKernelGGL(k_cvt_w, dim3(768), dim3(256), 0, stream, wqkv, 768, WQH, WQL);
    hipLaunchKernelGGL(k_cvt_w, dim3(256), dim3(256), 0, stream, wp, 256, WPH, WPL);
    hipLaunchKernelGGL(k_region_fused, dim3(512), dim3(256), 0, stream,
                       x, wqkv, bqkv, wg1, bg1, wg2, bg2, QKVR, SIG, XH, XL);
    hipLaunchKernelGGL(k_topk_gauss, dim3(512), dim3(64), 0, stream, QKVR, SIG, TOPK, GWT);
    hipLaunchKernelGGL(k_mm_qkv, dim3(6, 196), dim3(256), 0, stream,
                       XH, XL, WQH, WQL, bqkv, Qp, Kp, Vp);
    hipLaunchKernelGGL(k_transpose_v, dim3(512), dim3(256), 0, stream,
                       Vp, Vtp, dwk, dwb, ATTp);
    hipLaunchKernelGGL(k_attn, dim3(1024), dim3(256), 0, stream,
                       Qp, Kp, Vtp, TOPK, GWT, ATTp);
    hipLaunchKernelGGL(k_mm_proj, dim3(2, 196), dim3(256), 0, stream,
                       ATTp, WPH, WPL, bp, out);
}

// Round 9
// 294.316 us; speedup vs baseline: 1.1699x; 1.1296x over previous
//
#include <hip/hip_runtime.h>
#include <math.h>

#define SCALE 0.17677669529663687f  /* (256/8)^-0.5 */

typedef short short8 __attribute__((ext_vector_type(8)));
typedef float f32x4 __attribute__((ext_vector_type(4)));

// ---------------------------------------------------------------------------
__device__ __forceinline__ int token_row_addr(int m) {
    int b = m / 3136;
    int rem = m - b * 3136;
    int s = rem / 49;
    int tok = rem - s * 49;
    int h = (s >> 3) * 7 + tok / 7;
    int w = (s & 7) * 7 + (tok % 7);
    return (b * 56 + h) * 56 + w;
}

__device__ __forceinline__ void split2(float x, unsigned short& h, unsigned short& l) {
    unsigned int u = __float_as_uint(x);
    h = (unsigned short)(u >> 16);
    float hf = __uint_as_float(u & 0xFFFF0000u);
    l = (unsigned short)(__float_as_uint(x - hf) >> 16);
}

__device__ __forceinline__ unsigned int pack2(float x) {
    unsigned short h, l;
    split2(x, h, l);
    return ((unsigned int)h << 16) | l;
}

__device__ __forceinline__ float b2f(unsigned short u) {
    return __uint_as_float(((unsigned int)u) << 16);
}

__device__ __forceinline__ float unpack_f(unsigned int u) {
    return b2f((unsigned short)(u >> 16)) + b2f((unsigned short)(u & 0xFFFFu));
}

__device__ __forceinline__ void unpack_u4(uint4 a, uint4 b, short8& h, short8& l) {
    h[0] = (short)(a.x >> 16); l[0] = (short)(a.x & 0xFFFFu);
    h[1] = (short)(a.y >> 16); l[1] = (short)(a.y & 0xFFFFu);
    h[2] = (short)(a.z >> 16); l[2] = (short)(a.z & 0xFFFFu);
    h[3] = (short)(a.w >> 16); l[3] = (short)(a.w & 0xFFFFu);
    h[4] = (short)(b.x >> 16); l[4] = (short)(b.x & 0xFFFFu);
    h[5] = (short)(b.y >> 16); l[5] = (short)(b.y & 0xFFFFu);
    h[6] = (short)(b.z >> 16); l[6] = (short)(b.z & 0xFFFFu);
    h[7] = (short)(b.w >> 16); l[7] = (short)(b.w & 0xFFFFu);
}

__device__ __forceinline__ void load_unpack8(const unsigned int* g, short8& h, short8& l) {
    uint4 a = *(const uint4*)g;
    uint4 b = *(const uint4*)(g + 4);
    unpack_u4(a, b, h, l);
}

__device__ __forceinline__ void gload16(const unsigned short* g, unsigned short* l) {
    __builtin_amdgcn_global_load_lds(
        (const __attribute__((address_space(1))) unsigned int*)g,
        (__attribute__((address_space(3))) unsigned int*)l, 16, 0, 0);
}

// ---------------------------------------------------------------------------
// converter (weights only; x conversion fused into k_region_fused)
__global__ void k_cvt_w(const float* __restrict__ w, int ncols,
                        unsigned short* __restrict__ whi, unsigned short* __restrict__ wlo) {
    int n = blockIdx.x;
    int k = threadIdx.x;
    float v = w[(size_t)k * ncols + n];
    unsigned short h, l;
    split2(v, h, l);
    whi[(size_t)n * 256 + k] = h;
    wlo[(size_t)n * 256 + k] = l;
}

// ---------------------------------------------------------------------------
// K0: fused region path: x->bf16 split store + mean -> qkv_r -> gating.
// grid 512 (= b*64+s), block 256. De-serialized: 7 partial sums in the x-loop
// (MLP ~7 instead of 1), unroll-8 GEMM loop, gating-1 on all 256 threads,
// gating-2 as two wave-wide shfl reductions.
__global__ void k_region_fused(const float* __restrict__ x, const float* __restrict__ wqkv,
                               const float* __restrict__ bqkv, const float* __restrict__ wg1,
                               const float* __restrict__ bg1, const float* __restrict__ wg2,
                               const float* __restrict__ bg2, float* __restrict__ qkvr,
                               float* __restrict__ sig,
                               unsigned short* __restrict__ xhi,
                               unsigned short* __restrict__ xlo) {
    __shared__ float xs[256];
    __shared__ float qbuf[256];
    __shared__ float hp[4][64];
    __shared__ float hs[64];
    int blk = blockIdx.x;
    int b = blk >> 6, s = blk & 63;
    int t = threadIdx.x;
    int hy0 = (s >> 3) * 7, wx0 = (s & 7) * 7;
    const float* xb = x + ((size_t)b * 56 * 56) * 256 + t;
    size_t mbase = (size_t)blk * 49 * 256 + t;

    // phase 1: x read + split store + mean, 7 independent accumulator chains
    float ps[7];
#pragma unroll
    for (int i = 0; i < 7; ++i) ps[i] = 0.f;
#pragma unroll
    for (int tt = 0; tt < 49; ++tt) {
        int h = hy0 + tt / 7, w = wx0 + (tt % 7);
        float v = xb[(size_t)(h * 56 + w) * 256];
        ps[tt % 7] += v;
        unsigned short hi, lo;
        split2(v, hi, lo);
        xhi[mbase + (size_t)tt * 256] = hi;
        xlo[mbase + (size_t)tt * 256] = lo;
    }
    float sum = ((ps[0] + ps[1]) + (ps[2] + ps[3])) + ((ps[4] + ps[5]) + ps[6]);
    xs[t] = sum * (1.0f / 49.0f);
    __syncthreads();

    // phase 2: qkv_r = mean @ wqkv (+bias), deep unroll for L2 MLP
    float a0 = 0.f, a1 = 0.f, a2 = 0.f;
#pragma unroll 8
    for (int k = 0; k < 256; ++k) {
        float xv = xs[k];
        const float* wrow = wqkv + (size_t)k * 768;
        a0 += xv * wrow[t];
        a1 += xv * wrow[t + 256];
        a2 += xv * wrow[t + 512];
    }
    float q = a0 + bqkv[t];
    qbuf[t] = q;
    float* o = qkvr + (size_t)blk * 768;
    o[t]       = q;
    o[t + 256] = a1 + bqkv[t + 256];
    o[t + 512] = a2 + bqkv[t + 512];
    __syncthreads();

    // phase 3: g1 = relu(q @ wg1 + b), all 256 threads (4 k-quarters x 64 h)
    {
        int hcol = t & 63, qq = t >> 6;
        float pacc = 0.f;
#pragma unroll 8
        for (int k = qq * 64; k < qq * 64 + 64; ++k)
            pacc += qbuf[k] * wg1[(size_t)k * 64 + hcol];
        hp[qq][hcol] = pacc;
    }
    __syncthreads();
    if (t < 64)
        hs[t] = fmaxf(bg1[t] + hp[0][t] + hp[1][t] + hp[2][t] + hp[3][t], 0.f);
    __syncthreads();

    // phase 4: gp = hs @ wg2 + b -> softplus, two wave-wide shfl reductions
    if (t < 128) {
        int col = t >> 6, m = t & 63;
        float p = hs[m] * wg2[m * 2 + col];
#pragma unroll
        for (int off = 1; off < 64; off <<= 1)
            p += __shfl_xor(p, off, 64);
        if (m == 0) {
            float gp = p + bg2[col];
            float sp = fmaxf(gp, 0.f) + log1pf(expf(-fabsf(gp)));
            sig[blk * 2 + col] = sp + 0.5f;
        }
    }
}

__global__ void k_topk_gauss(const float* __restrict__ qkvr, const float* __restrict__ sig,
                             int* __restrict__ topk, float* __restrict__ gwt) {
    __shared__ float A[64];
    __shared__ float G[64];
    __shared__ int idxs[4];
    __shared__ float gsum_s;
    int blk = blockIdx.x;
    int b = blk >> 6, s = blk & 63;
    int z = threadIdx.x;
    const float* qr = qkvr + (size_t)blk * 768;
    const float* kr = qkvr + (size_t)(b * 64 + z) * 768 + 256;
    float acc = 0.f;
#pragma unroll 4
    for (int k = 0; k < 256; k += 4) {
        float4 q4 = *(const float4*)(qr + k);
        float4 k4 = *(const float4*)(kr + k);
        acc += q4.x * k4.x + q4.y * k4.y + q4.z * k4.z + q4.w * k4.w;
    }
    A[z] = acc * SCALE;
    float s0 = sig[blk * 2 + 0], s1 = sig[blk * 2 + 1];
    float dx = (float)((z & 7) - (s & 7));
    float dy = (float)((z >> 3) - (s >> 3));
    float t0 = dx / s0, t1 = dy / s1;
    float zz = t0 * t0 + t1 * t1;
    G[z] = expf(-0.5f * zz);
    __syncthreads();
    if (z == 0) {
        float gs = 0.f;
        for (int m = 0; m < 64; ++m) gs += G[m];
        gsum_s = gs + 1e-6f;
        for (int it = 0; it < 4; ++it) {
            int best = 0;
            float bv = A[0];
            for (int m = 1; m < 64; ++m) {
                if (A[m] > bv) { bv = A[m]; best = m; }
            }
            idxs[it] = best;
            A[best] = -3.0e38f;
        }
    }
    __syncthreads();
    if (z < 4) {
        int id = idxs[z];
        topk[blk * 4 + z] = id;
        gwt[blk * 4 + z] = G[id] / gsum_s;
    }
}

// ---------------------------------------------------------------------------
// K1: qkv GEMM, split-bf16 MFMA, 128x128 tile, BK=32. grid (6, 196).
__global__ __launch_bounds__(256) void k_mm_qkv(
    const unsigned short* __restrict__ xhi, const unsigned short* __restrict__ xlo,
    const unsigned short* __restrict__ whi, const unsigned short* __restrict__ wlo,
    const float* __restrict__ bqkv,
    unsigned int* __restrict__ Qp, unsigned int* __restrict__ Kp,
    unsigned int* __restrict__ Vp) {
    __shared__ __align__(16) unsigned short Ah[4096];
    __shared__ __align__(16) unsigned short Al[4096];
    __shared__ __align__(16) unsigned short Bh[4096];
    __shared__ __align__(16) unsigned short Bl[4096];
    int tid = threadIdx.x;
    int ln = tid & 63, wv = tid >> 6;
    int m0 = blockIdx.y * 128, n0 = blockIdx.x * 128;
    int mrow = (wv >> 1) * 64, ncol = (wv & 1) * 64;

    int lrow = ln >> 2, lseg = (ln & 3) * 8;
    const unsigned short* gA0 = xhi + (size_t)(m0 + wv * 32 + lrow) * 256 + lseg;
    const unsigned short* gA1 = gA0 + 16 * 256;
    const unsigned short* gAl0 = xlo + (size_t)(m0 + wv * 32 + lrow) * 256 + lseg;
    const unsigned short* gAl1 = gAl0 + 16 * 256;
    const unsigned short* gB0 = whi + (size_t)(n0 + wv * 32 + lrow) * 256 + lseg;
    const unsigned short* gB1 = gB0 + 16 * 256;
    const unsigned short* gBl0 = wlo + (size_t)(n0 + wv * 32 + lrow) * 256 + lseg;
    const unsigned short* gBl1 = gBl0 + 16 * 256;
    unsigned short* lA0 = &Ah[(wv * 32) * 32];
    unsigned short* lA1 = &Ah[(wv * 32 + 16) * 32];
    unsigned short* lAl0 = &Al[(wv * 32) * 32];
    unsigned short* lAl1 = &Al[(wv * 32 + 16) * 32];
    unsigned short* lB0 = &Bh[(wv * 32) * 32];
    unsigned short* lB1 = &Bh[(wv * 32 + 16) * 32];
    unsigned short* lBl0 = &Bl[(wv * 32) * 32];
    unsigned short* lBl1 = &Bl[(wv * 32 + 16) * 32];

    int fm = ln & 15, fq = (ln >> 4) * 8;
    f32x4 acc[4][4];
#pragma unroll
    for (int i = 0; i < 4; ++i)
#pragma unroll
        for (int j = 0; j < 4; ++j) acc[i][j] = (f32x4){0.f, 0.f, 0.f, 0.f};

#pragma unroll 1
    for (int kc = 0; kc < 8; ++kc) {
        if (kc) __syncthreads();
        gload16(gA0, lA0); gload16(gA1, lA1);
        gload16(gAl0, lAl0); gload16(gAl1, lAl1);
        gload16(gB0, lB0); gload16(gB1, lB1);
        gload16(gBl0, lBl0); gload16(gBl1, lBl1);
        gA0 += 32; gA1 += 32; gAl0 += 32; gAl1 += 32;
        gB0 += 32; gB1 += 32; gBl0 += 32; gBl1 += 32;
        __syncthreads();

        short8 ah[4], bh[4], xx[4];
#pragma unroll
        for (int mi = 0; mi < 4; ++mi)
            ah[mi] = *(const short8*)&Ah[(mrow + mi * 16 + fm) * 32 + fq];
#pragma unroll
        for (int ni = 0; ni < 4; ++ni)
            bh[ni] = *(const short8*)&Bh[(ncol + ni * 16 + fm) * 32 + fq];
#pragma unroll
        for (int mi = 0; mi < 4; ++mi)
#pragma unroll
            for (int ni = 0; ni < 4; ++ni)
                acc[mi][ni] = __builtin_amdgcn_mfma_f32_16x16x32_bf16(ah[mi], bh[ni], acc[mi][ni], 0, 0, 0);
#pragma unroll
        for (int mi = 0; mi < 4; ++mi)
            xx[mi] = *(const short8*)&Al[(mrow + mi * 16 + fm) * 32 + fq];
#pragma unroll
        for (int mi = 0; mi < 4; ++mi)
#pragma unroll
            for (int ni = 0; ni < 4; ++ni)
                acc[mi][ni] = __builtin_amdgcn_mfma_f32_16x16x32_bf16(xx[mi], bh[ni], acc[mi][ni], 0, 0, 0);
#pragma unroll
        for (int ni = 0; ni < 4; ++ni)
            xx[ni] = *(const short8*)&Bl[(ncol + ni * 16 + fm) * 32 + fq];
#pragma unroll
        for (int mi = 0; mi < 4; ++mi)
#pragma unroll
            for (int ni = 0; ni < 4; ++ni)
                acc[mi][ni] = __builtin_amdgcn_mfma_f32_16x16x32_bf16(ah[mi], xx[ni], acc[mi][ni], 0, 0, 0);
    }

    int nb = n0 >> 7;
    unsigned int* dst = (nb < 2) ? Qp : (nb < 4) ? Kp : Vp;
    int qrow = (ln >> 4) * 4;
#pragma unroll
    for (int ni = 0; ni < 4; ++ni) {
        int col = (n0 & 255) + ncol + ni * 16 + fm;
        float bias = bqkv[n0 + ncol + ni * 16 + fm];
#pragma unroll
        for (int mi = 0; mi < 4; ++mi) {
#pragma unroll
            for (int r = 0; r < 4; ++r) {
                int m = m0 + mrow + mi * 16 + qrow + r;
                dst[(size_t)m * 256 + col] = pack2(acc[mi][ni][r] + bias);
            }
        }
    }
}

// ---------------------------------------------------------------------------
// K1b: transpose Vp -> Vtp[win][c][64] packed (pads zeroed) AND fused dwconv
// -> ATTp initial value. grid 512, block 256.
__global__ __launch_bounds__(256) void k_transpose_v(
    const unsigned int* __restrict__ Vp, unsigned int* __restrict__ Vtp,
    const float* __restrict__ dwk, const float* __restrict__ dwb,
    unsigned int* __restrict__ ATTp) {
    __shared__ unsigned int T[49][257];
    int win = blockIdx.x;
    int tid = threadIdx.x;
#pragma unroll 1
    for (int i = tid; i < 49 * 64; i += 256) {
        int tok = i >> 6, cq = (i & 63) * 4;
        uint4 v = *(const uint4*)&Vp[((size_t)win * 49 + tok) * 256 + cq];
        T[tok][cq + 0] = v.x;
        T[tok][cq + 1] = v.y;
        T[tok][cq + 2] = v.z;
        T[tok][cq + 3] = v.w;
    }
    __syncthreads();
#pragma unroll 1
    for (int it = 0; it < 8; ++it) {
        int item = tid + it * 256;
        int c = item >> 3, t8 = (item & 7) * 8;
        uint4 o0, o1;
        o0.x = (t8 + 0 < 49) ? T[t8 + 0][c] : 0u;
        o0.y = (t8 + 1 < 49) ? T[t8 + 1][c] : 0u;
        o0.z = (t8 + 2 < 49) ? T[t8 + 2][c] : 0u;
        o0.w = (t8 + 3 < 49) ? T[t8 + 3][c] : 0u;
        o1.x = (t8 + 4 < 49) ? T[t8 + 4][c] : 0u;
        o1.y = (t8 + 5 < 49) ? T[t8 + 5][c] : 0u;
        o1.z = (t8 + 6 < 49) ? T[t8 + 6][c] : 0u;
        o1.w = (t8 + 7 < 49) ? T[t8 + 7][c] : 0u;
        size_t o = (size_t)win * 16384 + (size_t)c * 64 + t8;
        *(uint4*)&Vtp[o] = o0;
        *(uint4*)&Vtp[o + 4] = o1;
    }

    // fused dwconv: thread tid owns channel c = tid for all 49 tokens.
    {
        int c = tid;
        float dk[9];
#pragma unroll
        for (int t = 0; t < 9; ++t) dk[t] = dwk[(size_t)t * 256 + c];
        float db = dwb[c];
#pragma unroll 1
        for (int py = 0; py < 7; ++py) {
#pragma unroll 1
            for (int px = 0; px < 7; ++px) {
                float vd = db;
#pragma unroll
                for (int dy = 0; dy < 3; ++dy) {
                    int yy = py + dy - 1;
                    if (yy < 0 || yy > 6) continue;   // wave-uniform branch
#pragma unroll
                    for (int dx = 0; dx < 3; ++dx) {
                        int xx = px + dx - 1;
                        if (xx < 0 || xx > 6) continue;  // wave-uniform branch
                        vd += unpack_f(T[yy * 7 + xx][c]) * dk[dy * 3 + dx];
                    }
                }
                int w = py * 7 + px;
                ATTp[((size_t)win * 49 + w) * 256 + c] = pack2(vd);
            }
        }
    }
}

// ---------------------------------------------------------------------------
// K2: FUSED attention: QK^T + softmax + PV + ATTp RMW. grid 1024, block 256.
__global__ __launch_bounds__(256) void k_attn(
    const unsigned int* __restrict__ Qp, const unsigned int* __restrict__ Kp,
    const unsigned int* __restrict__ Vtp,
    const int* __restrict__ topk, const float* __restrict__ gwt,
    unsigned int* __restrict__ ATTp) {
    __shared__ __align__(16) unsigned int Ps[32][260];
    __shared__ float redm[4][32];
    __shared__ float reds[4][32];
    __shared__ float gmax[32];
    __shared__ float ginv[32];
    __shared__ int regs_s[4];
    int blk = blockIdx.x;
    int batch = blk & 7, idx = blk >> 3;
    int win = (batch << 6) | (idx >> 1);
    int wh = idx & 1;
    int b = batch;
    int tid = threadIdx.x, ln = tid & 63, wv = tid >> 6;
    int fm = ln & 15, g = ln >> 4, fq = g * 8;

    int myreg = topk[win * 4 + wv];
    float gw = gwt[win * 4 + wv];
    float sg = SCALE * gw;
    size_t qbase = (size_t)win * 49 * 256;
    size_t kbase = (size_t)(b * 64 + myreg) * 49 * 256;
    if (ln == 0) regs_s[wv] = myreg;

    // ---- phase 1: QK^T (wave = region wv) ----
    int arow[2];
#pragma unroll
    for (int mi = 0; mi < 2; ++mi) {
        int w = wh * 32 + mi * 16 + fm;
        arow[mi] = (w < 49) ? w : 48;
    }

    f32x4 acc[2][4];
#pragma unroll
    for (int i = 0; i < 2; ++i)
#pragma unroll
        for (int j = 0; j < 4; ++j) acc[i][j] = (f32x4){0.f, 0.f, 0.f, 0.f};

#pragma unroll 2
    for (int kc = 0; kc < 256; kc += 32) {
        short8 ah[2], al[2], bh[4], bl[4];
#pragma unroll
        for (int mi = 0; mi < 2; ++mi)
            load_unpack8(&Qp[qbase + (size_t)arow[mi] * 256 + kc + fq], ah[mi], al[mi]);
#pragma unroll
        for (int ni = 0; ni < 4; ++ni) {
            int tok = ni * 16 + fm;
            int trow = (tok < 49) ? tok : 48;
            load_unpack8(&Kp[kbase + (size_t)trow * 256 + kc + fq], bh[ni], bl[ni]);
        }
#pragma unroll
        for (int mi = 0; mi < 2; ++mi)
#pragma unroll
            for (int ni = 0; ni < 4; ++ni) {
                acc[mi][ni] = __builtin_amdgcn_mfma_f32_16x16x32_bf16(ah[mi], bh[ni], acc[mi][ni], 0, 0, 0);
                acc[mi][ni] = __builtin_amdgcn_mfma_f32_16x16x32_bf16(al[mi], bh[ni], acc[mi][ni], 0, 0, 0);
                acc[mi][ni] = __builtin_amdgcn_mfma_f32_16x16x32_bf16(ah[mi], bl[ni], acc[mi][ni], 0, 0, 0);
            }
    }

#pragma unroll
    for (int mi = 0; mi < 2; ++mi)
#pragma unroll
        for (int ni = 0; ni < 4; ++ni) acc[mi][ni] *= sg;

    // ---- softmax (block-wide over 4 regions) ----
    float rmax[2][4];
#pragma unroll
    for (int mi = 0; mi < 2; ++mi)
#pragma unroll
        for (int r = 0; r < 4; ++r) rmax[mi][r] = -3.0e38f;
#pragma unroll
    for (int mi = 0; mi < 2; ++mi)
#pragma unroll
        for (int ni = 0; ni < 4; ++ni) {
            if (ni * 16 + fm < 49) {
#pragma unroll
                for (int r = 0; r < 4; ++r)
                    rmax[mi][r] = fmaxf(rmax[mi][r], acc[mi][ni][r]);
            }
        }
#pragma unroll
    for (int off = 1; off < 16; off <<= 1)
#pragma unroll
        for (int mi = 0; mi < 2; ++mi)
#pragma unroll
            for (int r = 0; r < 4; ++r)
                rmax[mi][r] = fmaxf(rmax[mi][r], __shfl_xor(rmax[mi][r], off, 64));
    if (fm == 0) {
#pragma unroll
        for (int mi = 0; mi < 2; ++mi)
#pragma unroll
            for (int r = 0; r < 4; ++r)
                redm[wv][mi * 16 + g * 4 + r] = rmax[mi][r];
    }
    __syncthreads();
    if (tid < 32)
        gmax[tid] = fmaxf(fmaxf(redm[0][tid], redm[1][tid]),
                          fmaxf(redm[2][tid], redm[3][tid]));
    __syncthreads();

    float gm[2][4];
#pragma unroll
    for (int mi = 0; mi < 2; ++mi)
#pragma unroll
        for (int r = 0; r < 4; ++r) gm[mi][r] = gmax[mi * 16 + g * 4 + r];
    float rsum[2][4];
#pragma unroll
    for (int mi = 0; mi < 2; ++mi)
#pragma unroll
        for (int r = 0; r < 4; ++r) rsum[mi][r] = 0.f;
#pragma unroll
    for (int mi = 0; mi < 2; ++mi)
#pragma unroll
        for (int ni = 0; ni < 4; ++ni) {
            bool valid = (ni * 16 + fm) < 49;
#pragma unroll
            for (int r = 0; r < 4; ++r) {
                float e = valid ? __expf(acc[mi][ni][r] - gm[mi][r]) : 0.f;
                acc[mi][ni][r] = e;
                rsum[mi][r] += e;
            }
        }
#pragma unroll
    for (int off = 1; off < 16; off <<= 1)
#pragma unroll
        for (int mi = 0; mi < 2; ++mi)
#pragma unroll
            for (int r = 0; r < 4; ++r)
                rsum[mi][r] += __shfl_xor(rsum[mi][r], off, 64);
    if (fm == 0) {
#pragma unroll
        for (int mi = 0; mi < 2; ++mi)
#pragma unroll
            for (int r = 0; r < 4; ++r)
                reds[wv][mi * 16 + g * 4 + r] = rsum[mi][r];
    }
    __syncthreads();
    if (tid < 32)
        ginv[tid] = 1.0f / (reds[0][tid] + reds[1][tid] + reds[2][tid] + reds[3][tid]);
    __syncthreads();

    // ---- packed P into LDS (rows >=49 get zeros) ----
#pragma unroll
    for (int mi = 0; mi < 2; ++mi) {
#pragma unroll
        for (int r = 0; r < 4; ++r) {
            int rowb = mi * 16 + g * 4 + r;
            int w = wh * 32 + rowb;
            float giv = (w < 49) ? ginv[rowb] * gw : 0.f;
#pragma unroll
            for (int ni = 0; ni < 4; ++ni) {
                float p = acc[mi][ni][r] * giv;
                Ps[rowb][wv * 64 + ni * 16 + fm] = pack2(p);
            }
        }
    }

    // ---- prefetch ATTp RMW values (latency hides under barrier + PV) ----
    int ncol = wv * 64;
    unsigned int attv[4][2][4];
#pragma unroll
    for (int ni = 0; ni < 4; ++ni) {
        int c = ncol + ni * 16 + fm;
#pragma unroll
        for (int mi = 0; mi < 2; ++mi) {
#pragma unroll
            for (int rr = 0; rr < 4; ++rr) {
                int w = wh * 32 + mi * 16 + g * 4 + rr;
                attv[ni][mi][rr] = (w < 49) ? ATTp[((size_t)win * 49 + w) * 256 + c] : 0u;
            }
        }
    }
    __syncthreads();

    // ---- phase 2: PV (wave = 64-col strip) ----
    f32x4 oacc[2][4];
#pragma unroll
    for (int i = 0; i < 2; ++i)
#pragma unroll
        for (int j = 0; j < 4; ++j) oacc[i][j] = (f32x4){0.f, 0.f, 0.f, 0.f};

#pragma unroll 2
    for (int r = 0; r < 4; ++r) {
        int reg = regs_s[r];
        size_t vbase = (size_t)(b * 64 + reg) * 16384;
#pragma unroll
        for (int half = 0; half < 2; ++half) {
            int kc = r * 64 + half * 32;
            int tokoff = half * 32;
            short8 ah[2], al[2], bh[4], bl[4];
#pragma unroll
            for (int mi = 0; mi < 2; ++mi) {
                const unsigned int* p = &Ps[mi * 16 + fm][kc + fq];
                unpack_u4(*(const uint4*)p, *(const uint4*)(p + 4), ah[mi], al[mi]);
            }
#pragma unroll
            for (int ni = 0; ni < 4; ++ni)
                load_unpack8(&Vtp[vbase + (size_t)(ncol + ni * 16 + fm) * 64 + tokoff + fq], bh[ni], bl[ni]);
#pragma unroll
            for (int mi = 0; mi < 2; ++mi)
#pragma unroll
                for (int ni = 0; ni < 4; ++ni) {
                    oacc[mi][ni] = __builtin_amdgcn_mfma_f32_16x16x32_bf16(ah[mi], bh[ni], oacc[mi][ni], 0, 0, 0);
                    oacc[mi][ni] = __builtin_amdgcn_mfma_f32_16x16x32_bf16(al[mi], bh[ni], oacc[mi][ni], 0, 0, 0);
                    oacc[mi][ni] = __builtin_amdgcn_mfma_f32_16x16x32_bf16(ah[mi], bl[ni], oacc[mi][ni], 0, 0, 0);
                }
        }
    }

    // ---- epilogue: add prefetched dwconv values, repack, store ----
#pragma unroll
    for (int ni = 0; ni < 4; ++ni) {
        int c = ncol + ni * 16 + fm;
#pragma unroll
        for (int mi = 0; mi < 2; ++mi) {
#pragma unroll
            for (int rr = 0; rr < 4; ++rr) {
                int w = wh * 32 + mi * 16 + g * 4 + rr;
                if (w < 49) {
                    size_t i = ((size_t)win * 49 + w) * 256 + c;
                    ATTp[i] = pack2(oacc[mi][ni][rr] + unpack_f(attv[ni][mi][rr]));
                }
            }
        }
    }
}

// ---------------------------------------------------------------------------
// K3: proj GEMM, split-bf16 MFMA. A = packed ATT staged into padded LDS.
__global__ __launch_bounds__(256) void k_mm_proj(
    const unsigned int* __restrict__ Ap,
    const unsigned short* __restrict__ whi, const unsigned short* __restrict__ wlo,
    const float* __restrict__ bp, float* __restrict__ out) {
    __shared__ __align__(16) unsigned int As[128 * 36];
    __shared__ __align__(16) unsigned short Bh[4096];
    __shared__ __align__(16) unsigned short Bl[4096];
    int tid = threadIdx.x;
    int ln = tid & 63, wv = tid >> 6;
    int m0 = blockIdx.y * 128, n0 = blockIdx.x * 128;
    int mrow = (wv >> 1) * 64, ncol = (wv & 1) * 64;

    int lrow = ln >> 2, lseg = (ln & 3) * 8;
    const unsigned short* gB0 = whi + (size_t)(n0 + wv * 32 + lrow) * 256 + lseg;
    const unsigned short* gB1 = gB0 + 16 * 256;
    const unsigned short* gBl0 = wlo + (size_t)(n0 + wv * 32 + lrow) * 256 + lseg;
    const unsigned short* gBl1 = gBl0 + 16 * 256;
    unsigned short* lB0 = &Bh[(wv * 32) * 32];
    unsigned short* lB1 = &Bh[(wv * 32 + 16) * 32];
    unsigned short* lBl0 = &Bl[(wv * 32) * 32];
    unsigned short* lBl1 = &Bl[(wv * 32 + 16) * 32];

    int arow = ln >> 3, akk = (ln & 7) * 4;
    int fm = ln & 15, fq = (ln >> 4) * 8;
    f32x4 acc[4][4];
#pragma unroll
    for (int i = 0; i < 4; ++i)
#pragma unroll
        for (int j = 0; j < 4; ++j) acc[i][j] = (f32x4){0.f, 0.f, 0.f, 0.f};

#pragma unroll 1
    for (int kc = 0; kc < 8; ++kc) {
        if (kc) __syncthreads();
        gload16(gB0, lB0); gload16(gB1, lB1);
        gload16(gBl0, lBl0); gload16(gBl1, lBl1);
        gB0 += 32; gB1 += 32; gBl0 += 32; gBl1 += 32;
#pragma unroll
        for (int it = 0; it < 4; ++it) {
            int row = wv * 32 + it * 8 + arow;
            uint4 v = *(const uint4*)&Ap[(size_t)(m0 + row) * 256 + kc * 32 + akk];
            *(uint4*)&As[row * 36 + akk] = v;
        }
        __syncthreads();

        short8 ah[4], al[4], bh[4], xx[4];
#pragma unroll
        for (int mi = 0; mi < 4; ++mi) {
            const unsigned int* p = &As[(mrow + mi * 16 + fm) * 36 + fq];
            unpack_u4(*(const uint4*)p, *(const uint4*)(p + 4), ah[mi], al[mi]);
        }
#pragma unroll
        for (int ni = 0; ni < 4; ++ni)
            bh[ni] = *(const short8*)&Bh[(ncol + ni * 16 + fm) * 32 + fq];
#pragma unroll
        for (int mi = 0; mi < 4; ++mi)
#pragma unroll
            for (int ni = 0; ni < 4; ++ni)
                acc[mi][ni] = __builtin_amdgcn_mfma_f32_16x16x32_bf16(ah[mi], bh[ni], acc[mi][ni], 0, 0, 0);
#pragma unroll
        for (int mi = 0; mi < 4; ++mi)
#pragma unroll
            for (int ni = 0; ni < 4; ++ni)
                acc[mi][ni] = __builtin_amdgcn_mfma_f32_16x16x32_bf16(al[mi], bh[ni], acc[mi][ni], 0, 0, 0);
#pragma unroll
        for (int ni = 0; ni < 4; ++ni)
            xx[ni] = *(const short8*)&Bl[(ncol + ni * 16 + fm) * 32 + fq];
#pragma unroll
        for (int mi = 0; mi < 4; ++mi)
#pragma unroll
            for (int ni = 0; ni < 4; ++ni)
                acc[mi][ni] = __builtin_amdgcn_mfma_f32_16x16x32_bf16(ah[mi], xx[ni], acc[mi][ni], 0, 0, 0);
    }

    int qrow = (ln >> 4) * 4;
#pragma unroll
    for (int mi = 0; mi < 4; ++mi) {
#pragma unroll
        for (int r = 0; r < 4; ++r) {
            int m = m0 + mrow + mi * 16 + qrow + r;
            size_t orow = (size_t)token_row_addr(m);
#pragma unroll
            for (int ni = 0; ni < 4; ++ni) {
                int col = n0 + ncol + ni * 16 + fm;
                out[orow * 256 + col] = acc[mi][ni][r] + bp[col];
            }
        }
    }
}

// ---------------------------------------------------------------------------
extern "C" void kernel_launch(void* const* d_in, const int* in_sizes, int n_in,
                              void* d_out, int out_size, void* d_ws, size_t ws_size,
                              hipStream_t stream) {
    const float* x    = (const float*)d_in[0];
    const float* wqkv = (const float*)d_in[1];
    const float* bqkv = (const float*)d_in[2];
    const float* wg1  = (const float*)d_in[3];
    const float* bg1  = (const float*)d_in[4];
    const float* wg2  = (const float*)d_in[5];
    const float* bg2  = (const float*)d_in[6];
    const float* dwk  = (const float*)d_in[7];
    const float* dwb  = (const float*)d_in[8];
    const float* wp   = (const float*)d_in[9];
    const float* bp   = (const float*)d_in[10];
    float* out = (float*)d_out;

    const size_t NTOT = (size_t)25088 * 256;     // 6,422,528
    const size_t VTSZ = (size_t)512 * 256 * 64;  // 8,388,608
    unsigned int* Qp  = (unsigned int*)d_ws;
    unsigned int* Kp  = Qp + NTOT;
    unsigned int* Vp  = Kp + NTOT;
    unsigned int* Vtp = Vp + NTOT;
    unsigned int* Pp  = Vtp + VTSZ;              // unused (kept for layout)
    unsigned short* XH = (unsigned short*)(Pp + VTSZ);  // x bf16 hi; later ATTp
    unsigned short* XL = XH + NTOT;                     // x bf16 lo
    unsigned int* ATTp = (unsigned int*)XH;             // alias (x dead after qkv)
    unsigned short* WQH = XL + NTOT;
    unsigned short* WQL = WQH + 768 * 256;
    unsigned short* WPH = WQL + 768 * 256;
    unsigned short* WPL = WPH + 256 * 256;
    float* QKVR = (float*)(WPL + 256 * 256);
    float* SIG  = QKVR + 512 * 768;
    float* GWT  = SIG + 1024;
    int*   TOPK = (int*)(GWT + 2048);

    hipLaunchKernelGGL(k_cvt_w, dim3(768), dim3(256), 0, stream, wqkv, 768, WQH, WQL);
    hipLaunchKernelGGL(k_cvt_w, dim3(256), dim3(256), 0, stream, wp, 256, WPH, WPL);
    hipLaunchKernelGGL(k_region_fused, dim3(512), dim3(256), 0, stream,
                       x, wqkv, bqkv, wg1, bg1, wg2, bg2, QKVR, SIG, XH, XL);
    hipLaunchKernelGGL(k_topk_gauss, dim3(512), dim3(64), 0, stream, QKVR, SIG, TOPK, GWT);
    hipLaunchKernelGGL(k_mm_qkv, dim3(6, 196), dim3(256), 0, stream,
                       XH, XL, WQH, WQL, bqkv, Qp, Kp, Vp);
    hipLaunchKernelGGL(k_transpose_v, dim3(512), dim3(256), 0, stream,
                       Vp, Vtp, dwk, dwb, ATTp);
    hipLaunchKernelGGL(k_attn, dim3(1024), dim3(256), 0, stream,
                       Qp, Kp, Vtp, TOPK, GWT, ATTp);
    hipLaunchKernelGGL(k_mm_proj, dim3(2, 196), dim3(256), 0, stream,
                       ATTp, WPH, WPL, bp, out);
}